// Round 1
// baseline (1161.053 us; speedup 1.0000x reference)
//
#include <hip/hip_runtime.h>
#include <cstdint>
#include <cstddef>

#define N_NODES 50000
#define N_EDGES 800000
#define HID 64
#define HEADS 4
#define N_GRAPHS 32
#define N_QUERY 4096

// ---- workspace layout (element offsets; all 4-byte elements, 16-elt aligned) ----
static constexpr size_t OFF_DEG   = 0;          // int[50000]
static constexpr size_t OFF_CNT   = 50000;      // float[32]
static constexpr size_t OFF_PSUM  = 50032;      // float[2048]
static constexpr size_t OFF_OFFS  = 52080;      // int[50001]
static constexpr size_t OFF_CURS  = 102096;     // int[50000]
static constexpr size_t OFF_CSR   = 152096;     // int[800000]
static constexpr size_t OFF_AL    = 952096;     // float[256]
static constexpr size_t OFF_AR    = 952352;     // float[256]
static constexpr size_t OFF_AE    = 952608;     // float[256]
static constexpr size_t OFF_SS    = 952864;     // float[128] scale/shift
static constexpr size_t OFF_EL    = 952992;     // float[200000]
static constexpr size_t OFF_ER    = 1152992;    // float[200000]
static constexpr size_t OFF_NODES = 1352992;    // float[3200000]
static constexpr size_t OFF_U     = 4552992;    // float[25600000]
static constexpr size_t OFF_RST   = 30152992;   // float[12800000]
static constexpr size_t OFF_X     = 42952992;   // float[3200000]
static constexpr size_t OFF_SCR   = 46152992;   // float[400000]  (3125 blocks x 128)
static constexpr size_t WS_TOTAL  = 46552992;   // elements

// A[k,h] = sum_d fc_w2[k, h*64+d] * attn[h,d]   (64x4 each)
__global__ void precompute_kernel(const float* __restrict__ fcw2, const float* __restrict__ fcew2,
                                  const float* __restrict__ attl2, const float* __restrict__ attr2,
                                  const float* __restrict__ atte2,
                                  float* __restrict__ Al, float* __restrict__ Ar, float* __restrict__ Ae)
{
    int tid = threadIdx.x;          // 256 threads
    int k = tid >> 2, h = tid & 3;
    float al = 0.f, ar = 0.f, ae = 0.f;
    for (int d = 0; d < 64; d++) {
        float wl = fcw2[k*256 + h*64 + d];
        float we = fcew2[k*256 + h*64 + d];
        al = fmaf(wl, attl2[h*64 + d], al);
        ar = fmaf(wl, attr2[h*64 + d], ar);
        ae = fmaf(we, atte2[h*64 + d], ae);
    }
    Al[k*4 + h] = al;
    Ar[k*4 + h] = ar;
    Ae[k*4 + h] = ae;
}

// nodes = node_feat @ Wp + bp ; el/er = nodes @ Al/Ar (wave-butterfly reduce)
__global__ __launch_bounds__(256) void node_proj_kernel(
    const float* __restrict__ nf, const float* __restrict__ wp, const float* __restrict__ bpn,
    const float* __restrict__ Al, const float* __restrict__ Ar,
    float* __restrict__ nodes, float* __restrict__ el, float* __restrict__ er)
{
    __shared__ float rows[4][64];
    int tid = threadIdx.x, w = tid >> 6, lane = tid & 63;
    int n = blockIdx.x * 4 + w;
    rows[w][lane] = nf[(size_t)n*64 + lane];
    __syncthreads();
    float acc = bpn[lane];
    for (int k = 0; k < 64; k++) acc = fmaf(rows[w][k], wp[k*64 + lane], acc);
    nodes[(size_t)n*64 + lane] = acc;
    float pl[4], pr[4];
#pragma unroll
    for (int h = 0; h < 4; h++) { pl[h] = acc * Al[lane*4 + h]; pr[h] = acc * Ar[lane*4 + h]; }
#pragma unroll
    for (int off = 32; off > 0; off >>= 1) {
#pragma unroll
        for (int h = 0; h < 4; h++) {
            pl[h] += __shfl_xor(pl[h], off, 64);
            pr[h] += __shfl_xor(pr[h], off, 64);
        }
    }
    if (lane == 0) {
#pragma unroll
        for (int h = 0; h < 4; h++) { el[(size_t)n*4 + h] = pl[h]; er[(size_t)n*4 + h] = pr[h]; }
    }
}

__global__ void hist_kernel(const int* __restrict__ dst, int* __restrict__ deg)
{
    int e = blockIdx.x * 256 + threadIdx.x;
    if (e < N_EDGES) atomicAdd(&deg[dst[e]], 1);
}

__global__ void prefix_kernel(const int* __restrict__ deg, int* __restrict__ offs, int* __restrict__ curs)
{
    __shared__ int lds[1024];
    __shared__ int carry;
    int tid = threadIdx.x;
    if (tid == 0) carry = 0;
    __syncthreads();
    for (int base = 0; base < N_NODES; base += 1024) {
        int i = base + tid;
        int v = (i < N_NODES) ? deg[i] : 0;
        lds[tid] = v;
        __syncthreads();
        for (int off = 1; off < 1024; off <<= 1) {
            int y = (tid >= off) ? lds[tid - off] : 0;
            __syncthreads();
            lds[tid] += y;
            __syncthreads();
        }
        int incl = lds[tid];
        int c0 = carry;
        if (i < N_NODES) { int ex = c0 + incl - v; offs[i] = ex; curs[i] = ex; }
        __syncthreads();
        if (tid == 1023) carry = c0 + lds[1023];
        __syncthreads();
    }
    if (tid == 0) offs[N_NODES] = carry;
}

__global__ void fill_kernel(const int* __restrict__ dst, int* __restrict__ curs, int* __restrict__ csr)
{
    int e = blockIdx.x * 256 + threadIdx.x;
    if (e < N_EDGES) {
        int slot = atomicAdd(&curs[dst[e]], 1);
        csr[slot] = e;
    }
}

// One wave per dst node. Online softmax over its in-edges; accumulate
// u[n][h][0:64]   = sum_e a_eh * nodes[src_e]   (t part)
// u[n][h][64:128] = sum_e a_eh * eproj_e        (s part)
__global__ __launch_bounds__(256) void edge_kernel(
    const int* __restrict__ offs, const int* __restrict__ csr, const int* __restrict__ src,
    const float* __restrict__ edge_feat, const float* __restrict__ wpe, const float* __restrict__ bpe,
    const float* __restrict__ Ae, const float* __restrict__ el, const float* __restrict__ er,
    const float* __restrict__ nodes, float* __restrict__ u)
{
    int wid = blockIdx.x * 4 + (threadIdx.x >> 6);
    wid = __builtin_amdgcn_readfirstlane(wid);
    if (wid >= N_NODES) return;
    int lane = threadIdx.x & 63;
    int start = offs[wid], end = offs[wid + 1];

    float wcol[16];
#pragma unroll
    for (int k = 0; k < 16; k++) wcol[k] = wpe[k*64 + lane];
    float bp = bpe[lane];
    float ae[4], erv[4];
#pragma unroll
    for (int h = 0; h < 4; h++) { ae[h] = Ae[lane*4 + h]; erv[h] = er[(size_t)wid*4 + h]; }

    float m[4], z[4], t[4], s[4];
#pragma unroll
    for (int h = 0; h < 4; h++) { m[h] = -1e30f; z[h] = 0.f; t[h] = 0.f; s[h] = 0.f; }

    for (int j = start; j < end; ++j) {
        int eid = csr[j];
        int sn  = src[eid];
        const float* ef = edge_feat + (size_t)eid * 16;
        float ep = bp;
#pragma unroll
        for (int k = 0; k < 16; k++) ep = fmaf(ef[k], wcol[k], ep);
        float ee[4];
#pragma unroll
        for (int h = 0; h < 4; h++) ee[h] = ep * ae[h];
#pragma unroll
        for (int off = 32; off > 0; off >>= 1) {
#pragma unroll
            for (int h = 0; h < 4; h++) ee[h] += __shfl_xor(ee[h], off, 64);
        }
        float nd = nodes[(size_t)sn*64 + lane];
        const float* elp = el + (size_t)sn * 4;
#pragma unroll
        for (int h = 0; h < 4; h++) {
            float l = elp[h] + erv[h] + ee[h];
            l = (l > 0.f) ? l : 0.2f * l;          // leaky relu 0.2
            float nm = fmaxf(m[h], l);
            float sc = __expf(m[h] - nm);
            float p  = __expf(l - nm);
            m[h] = nm;
            z[h] = z[h] * sc + p;
            t[h] = fmaf(t[h], sc, p * nd);
            s[h] = fmaf(s[h], sc, p * ep);
        }
    }
    float* up = u + (size_t)wid * 512;
#pragma unroll
    for (int h = 0; h < 4; h++) {
        float inv = (z[h] > 0.f) ? 1.f / z[h] : 0.f;
        up[h*128 + lane]      = t[h] * inv;
        up[h*128 + 64 + lane] = s[h] * inv;
    }
}

// rst[n, h*64+dd] = silu( t[n,h,:]@fcW_h + s[n,h,:]@fcEW_h + bias ), plus BN partial stats
__global__ __launch_bounds__(256) void conv_kernel(
    const float* __restrict__ u, const float* __restrict__ fcw2, const float* __restrict__ fcew2,
    const float* __restrict__ convb2, float* __restrict__ rst, float* __restrict__ scr)
{
    __shared__ float ul[16 * 512];
    __shared__ float red[512];
    int tid = threadIdx.x;
    int n0 = blockIdx.x * 16;
    for (int i = tid; i < 16*512; i += 256) ul[i] = u[(size_t)n0*512 + i];
    __syncthreads();
    int c = tid, h = tid >> 6;
    int baseA = h * 128, baseB = h * 128 + 64;
    float acc[16];
#pragma unroll
    for (int t2 = 0; t2 < 16; t2++) acc[t2] = 0.f;
    for (int k = 0; k < 64; k++) {
        float wA = fcw2[k*256 + c];
#pragma unroll
        for (int t2 = 0; t2 < 16; t2++) acc[t2] = fmaf(wA, ul[t2*512 + baseA + k], acc[t2]);
    }
    for (int k = 0; k < 64; k++) {
        float wB = fcew2[k*256 + c];
#pragma unroll
        for (int t2 = 0; t2 < 16; t2++) acc[t2] = fmaf(wB, ul[t2*512 + baseB + k], acc[t2]);
    }
    float bias = convb2[c];
    float psumv = 0.f, psqv = 0.f;
#pragma unroll
    for (int t2 = 0; t2 < 16; t2++) {
        float v = acc[t2] + bias;
        float r = v / (1.f + __expf(-v));          // silu
        rst[(size_t)(n0 + t2)*256 + c] = r;
        psumv += r; psqv += r * r;
    }
    red[c] = psumv; red[256 + c] = psqv;
    __syncthreads();
    if (tid < 64) {
        float sgm = red[tid] + red[64+tid] + red[128+tid] + red[192+tid];
        float sq  = red[256+tid] + red[320+tid] + red[384+tid] + red[448+tid];
        scr[(size_t)blockIdx.x*128 + tid]      = sgm;
        scr[(size_t)blockIdx.x*128 + 64 + tid] = sq;
    }
}

__global__ void bn_finalize_kernel(const float* __restrict__ scr, const float* __restrict__ gamma2,
                                   const float* __restrict__ beta2, float* __restrict__ ss)
{
    __shared__ float part[8][128];
    __shared__ float tot[128];
    int j = threadIdx.x & 127, chunk = threadIdx.x >> 7;   // 1024 threads
    float t = 0.f;
    for (int b = chunk; b < N_NODES/16; b += 8) t += scr[(size_t)b*128 + j];
    part[chunk][j] = t;
    __syncthreads();
    if (threadIdx.x < 128) {
        float sgm = 0.f;
        for (int c = 0; c < 8; c++) sgm += part[c][threadIdx.x];
        tot[threadIdx.x] = sgm;
    }
    __syncthreads();
    if (threadIdx.x < 64) {
        float inv = 1.f / (float)(N_NODES * HEADS);
        float mean = tot[threadIdx.x] * inv;
        float var  = tot[64 + threadIdx.x] * inv - mean * mean;
        float sc = gamma2[threadIdx.x] * rsqrtf(var + 1e-5f);
        ss[threadIdx.x]      = sc;
        ss[64 + threadIdx.x] = beta2[threadIdx.x] - mean * sc;
    }
}

// x = BN(rst) @ head_w + head_b ; pooled partial sums via atomics
__global__ __launch_bounds__(256) void head_kernel(
    const float* __restrict__ rst, const float* __restrict__ ss,
    const float* __restrict__ headw, const float* __restrict__ headb,
    const int* __restrict__ gids, float* __restrict__ x, float* __restrict__ psum)
{
    __shared__ float xl[16 * 256];
    int tid = threadIdx.x;
    int n0 = blockIdx.x * 16;
    for (int i = tid; i < 16*256; i += 256) {
        int ch = i & 63;
        xl[i] = fmaf(rst[(size_t)n0*256 + i], ss[ch], ss[64 + ch]);
    }
    __syncthreads();
    int c = tid & 63, g = tid >> 6;
    float hb = headb[c];
    float a[4] = {hb, hb, hb, hb};
    for (int k = 0; k < 256; k++) {
        float w = headw[k*64 + c];
#pragma unroll
        for (int t2 = 0; t2 < 4; t2++) a[t2] = fmaf(w, xl[(g*4 + t2)*256 + k], a[t2]);
    }
#pragma unroll
    for (int t2 = 0; t2 < 4; t2++) {
        int n = n0 + g*4 + t2;
        x[(size_t)n*64 + c] = a[t2];
        atomicAdd(&psum[(size_t)gids[n]*64 + c], a[t2]);
    }
}

__global__ void cnt_kernel(const int* __restrict__ gids, float* __restrict__ cnt)
{
    int n = blockIdx.x * 256 + threadIdx.x;
    if (n < N_NODES) atomicAdd(&cnt[gids[n]], 1.f);
}

__global__ void pooled_kernel(const float* __restrict__ psum, const float* __restrict__ cnt,
                              float* __restrict__ out)
{
    int i = blockIdx.x * 256 + threadIdx.x;
    if (i < N_GRAPHS * HID) out[i] = psum[i] / fmaxf(cnt[i >> 6], 1.f);
}

__global__ void gather_kernel(const float* __restrict__ x, const int* __restrict__ nidx,
                              float* __restrict__ outq)
{
    int i = blockIdx.x * 256 + threadIdx.x;
    if (i < N_QUERY * HID) {
        int q = i >> 6, c = i & 63;
        outq[i] = x[(size_t)nidx[q]*64 + c];
    }
}

extern "C" void kernel_launch(void* const* d_in, const int* in_sizes, int n_in,
                              void* d_out, int out_size, void* d_ws, size_t ws_size,
                              hipStream_t stream)
{
    const float* node_feat   = (const float*)d_in[0];
    const float* edge_feat   = (const float*)d_in[1];
    const float* node_proj_w = (const float*)d_in[2];
    const float* node_proj_b = (const float*)d_in[3];
    const float* edge_proj_w = (const float*)d_in[4];
    const float* edge_proj_b = (const float*)d_in[5];
    const float* fc_w        = (const float*)d_in[6];
    const float* fc_edge_w   = (const float*)d_in[7];
    const float* attn_l      = (const float*)d_in[8];
    const float* attn_r      = (const float*)d_in[9];
    const float* attn_e      = (const float*)d_in[10];
    const float* conv_bias   = (const float*)d_in[11];
    const float* bn_gamma    = (const float*)d_in[12];
    const float* bn_beta     = (const float*)d_in[13];
    const float* head_w      = (const float*)d_in[14];
    const float* head_b      = (const float*)d_in[15];
    const int*   src         = (const int*)d_in[16];
    const int*   dst         = (const int*)d_in[17];
    const int*   gids        = (const int*)d_in[18];
    const int*   nidx        = (const int*)d_in[19];

    if (ws_size < WS_TOTAL * sizeof(float)) return;  // workspace too small -> fail loudly

    float* ws  = (float*)d_ws;
    float* out = (float*)d_out;

    const int L2 = 2;
    const float* fcw2   = fc_w      + (size_t)L2 * HID * HEADS * HID;
    const float* fcew2  = fc_edge_w + (size_t)L2 * HID * HEADS * HID;
    const float* attl2  = attn_l    + (size_t)L2 * HEADS * HID;
    const float* attr2  = attn_r    + (size_t)L2 * HEADS * HID;
    const float* atte2  = attn_e    + (size_t)L2 * HEADS * HID;
    const float* convb2 = conv_bias + (size_t)L2 * HEADS * HID;
    const float* gamma2 = bn_gamma  + (size_t)L2 * HID;
    const float* beta2  = bn_beta   + (size_t)L2 * HID;

    int*   deg   = (int*)(ws + OFF_DEG);
    float* cnt   = ws + OFF_CNT;
    float* psum  = ws + OFF_PSUM;
    int*   offs  = (int*)(ws + OFF_OFFS);
    int*   curs  = (int*)(ws + OFF_CURS);
    int*   csr   = (int*)(ws + OFF_CSR);
    float* Al    = ws + OFF_AL;
    float* Ar    = ws + OFF_AR;
    float* Ae    = ws + OFF_AE;
    float* ss    = ws + OFF_SS;
    float* el    = ws + OFF_EL;
    float* er    = ws + OFF_ER;
    float* nodes = ws + OFF_NODES;
    float* u     = ws + OFF_U;
    float* rst   = ws + OFF_RST;
    float* x     = ws + OFF_X;
    float* scr   = ws + OFF_SCR;

    // zero: deg + cnt + psum (contiguous at ws start)
    hipMemsetAsync(d_ws, 0, OFF_OFFS * sizeof(float), stream);

    precompute_kernel<<<1, 256, 0, stream>>>(fcw2, fcew2, attl2, attr2, atte2, Al, Ar, Ae);
    node_proj_kernel<<<N_NODES/4, 256, 0, stream>>>(node_feat, node_proj_w, node_proj_b,
                                                    Al, Ar, nodes, el, er);
    hist_kernel<<<(N_EDGES + 255)/256, 256, 0, stream>>>(dst, deg);
    prefix_kernel<<<1, 1024, 0, stream>>>(deg, offs, curs);
    fill_kernel<<<(N_EDGES + 255)/256, 256, 0, stream>>>(dst, curs, csr);
    edge_kernel<<<N_NODES/4, 256, 0, stream>>>(offs, csr, src, edge_feat,
                                               edge_proj_w, edge_proj_b, Ae, el, er, nodes, u);
    conv_kernel<<<N_NODES/16, 256, 0, stream>>>(u, fcw2, fcew2, convb2, rst, scr);
    bn_finalize_kernel<<<1, 1024, 0, stream>>>(scr, gamma2, beta2, ss);
    head_kernel<<<N_NODES/16, 256, 0, stream>>>(rst, ss, head_w, head_b, gids, x, psum);
    cnt_kernel<<<(N_NODES + 255)/256, 256, 0, stream>>>(gids, cnt);
    pooled_kernel<<<(N_GRAPHS*HID + 255)/256, 256, 0, stream>>>(psum, cnt, out);
    gather_kernel<<<(N_QUERY*HID + 255)/256, 256, 0, stream>>>(x, nidx, out + N_GRAPHS*HID);
}

// Round 2
// 802.081 us; speedup vs baseline: 1.4476x; 1.4476x over previous
//
#include <hip/hip_runtime.h>
#include <cstdint>
#include <cstddef>

#define N_NODES 50000
#define N_EDGES 800000
#define HID 64
#define HEADS 4
#define N_GRAPHS 32
#define N_QUERY 4096

// ---- workspace layout (element offsets; all 4-byte elements, 16-elt aligned) ----
static constexpr size_t OFF_DEG   = 0;          // int[50000]
static constexpr size_t OFF_CNT   = 50000;      // (unused now)
static constexpr size_t OFF_GST   = 50032;      // int[33] graph boundaries
static constexpr size_t OFF_OFFS  = 52080;      // int[50001]
static constexpr size_t OFF_CURS  = 102096;     // int[50000]
static constexpr size_t OFF_CSR   = 152096;     // int[800000]
static constexpr size_t OFF_AL    = 952096;     // float[256]
static constexpr size_t OFF_AR    = 952352;     // float[256]
static constexpr size_t OFF_AE    = 952608;     // float[256]
static constexpr size_t OFF_SS    = 952864;     // float[128] scale/shift
static constexpr size_t OFF_EL    = 952992;     // float[200000]
static constexpr size_t OFF_ER    = 1152992;    // float[200000]
static constexpr size_t OFF_NODES = 1352992;    // float[3200000]
static constexpr size_t OFF_U     = 4552992;    // float[25600000]
static constexpr size_t OFF_RST   = 30152992;   // float[12800000]
static constexpr size_t OFF_X     = 42952992;   // float[3200000]
static constexpr size_t OFF_SCR   = 46152992;   // float[400000]  (3125 blocks x 128)
static constexpr size_t WS_TOTAL  = 46552992;   // elements

// A[k,h] = sum_d fc_w2[k, h*64+d] * attn[h,d]   (64x4 each)
__global__ void precompute_kernel(const float* __restrict__ fcw2, const float* __restrict__ fcew2,
                                  const float* __restrict__ attl2, const float* __restrict__ attr2,
                                  const float* __restrict__ atte2,
                                  float* __restrict__ Al, float* __restrict__ Ar, float* __restrict__ Ae)
{
    int tid = threadIdx.x;          // 256 threads
    int k = tid >> 2, h = tid & 3;
    float al = 0.f, ar = 0.f, ae = 0.f;
    for (int d = 0; d < 64; d++) {
        float wl = fcw2[k*256 + h*64 + d];
        float we = fcew2[k*256 + h*64 + d];
        al = fmaf(wl, attl2[h*64 + d], al);
        ar = fmaf(wl, attr2[h*64 + d], ar);
        ae = fmaf(we, atte2[h*64 + d], ae);
    }
    Al[k*4 + h] = al;
    Ar[k*4 + h] = ar;
    Ae[k*4 + h] = ae;
}

// nodes = node_feat @ Wp + bp ; el/er = nodes @ Al/Ar (wave-butterfly reduce)
__global__ __launch_bounds__(256) void node_proj_kernel(
    const float* __restrict__ nf, const float* __restrict__ wp, const float* __restrict__ bpn,
    const float* __restrict__ Al, const float* __restrict__ Ar,
    float* __restrict__ nodes, float* __restrict__ el, float* __restrict__ er)
{
    __shared__ float rows[4][64];
    int tid = threadIdx.x, w = tid >> 6, lane = tid & 63;
    int n = blockIdx.x * 4 + w;
    rows[w][lane] = nf[(size_t)n*64 + lane];
    __syncthreads();
    float acc = bpn[lane];
    for (int k = 0; k < 64; k++) acc = fmaf(rows[w][k], wp[k*64 + lane], acc);
    nodes[(size_t)n*64 + lane] = acc;
    float pl[4], pr[4];
#pragma unroll
    for (int h = 0; h < 4; h++) { pl[h] = acc * Al[lane*4 + h]; pr[h] = acc * Ar[lane*4 + h]; }
#pragma unroll
    for (int off = 32; off > 0; off >>= 1) {
#pragma unroll
        for (int h = 0; h < 4; h++) {
            pl[h] += __shfl_xor(pl[h], off, 64);
            pr[h] += __shfl_xor(pr[h], off, 64);
        }
    }
    if (lane == 0) {
#pragma unroll
        for (int h = 0; h < 4; h++) { el[(size_t)n*4 + h] = pl[h]; er[(size_t)n*4 + h] = pr[h]; }
    }
}

__global__ void hist_kernel(const int* __restrict__ dst, int* __restrict__ deg)
{
    int e = blockIdx.x * 256 + threadIdx.x;
    if (e < N_EDGES) atomicAdd(&deg[dst[e]], 1);
}

// shfl-based scan: 1024 threads = 16 waves; 49 chunks with sequential carry
__global__ __launch_bounds__(1024) void prefix_kernel(const int* __restrict__ deg,
                                                      int* __restrict__ offs, int* __restrict__ curs)
{
    __shared__ int wsum[16];
    __shared__ int carry_s;
    int tid = threadIdx.x, lane = tid & 63, w = tid >> 6;
    if (tid == 0) carry_s = 0;
    __syncthreads();
    for (int base = 0; base < N_NODES; base += 1024) {
        int i = base + tid;
        int v = (i < N_NODES) ? deg[i] : 0;
        int incl = v;
#pragma unroll
        for (int off = 1; off < 64; off <<= 1) {
            int y = __shfl_up(incl, off, 64);
            if (lane >= off) incl += y;
        }
        if (lane == 63) wsum[w] = incl;
        __syncthreads();
        int c0 = carry_s;
        int woff = 0;
#pragma unroll
        for (int k = 0; k < 15; k++) woff += (k < w) ? wsum[k] : 0;
        int ex = c0 + woff + incl - v;
        if (i < N_NODES) { offs[i] = ex; curs[i] = ex; }
        __syncthreads();
        if (tid == 1023) carry_s = c0 + woff + incl;
        __syncthreads();
    }
    if (tid == 0) offs[N_NODES] = carry_s;
}

__global__ void fill_kernel(const int* __restrict__ dst, int* __restrict__ curs, int* __restrict__ csr)
{
    int e = blockIdx.x * 256 + threadIdx.x;
    if (e < N_EDGES) {
        int slot = atomicAdd(&curs[dst[e]], 1);
        csr[slot] = e;
    }
}

// One wave per dst node. Online softmax over its in-edges; accumulate
// u[n][h][0:64]   = sum_e a_eh * nodes[src_e]   (t part)
// u[n][h][64:128] = sum_e a_eh * eproj_e        (s part)
__global__ __launch_bounds__(256) void edge_kernel(
    const int* __restrict__ offs, const int* __restrict__ csr, const int* __restrict__ src,
    const float* __restrict__ edge_feat, const float* __restrict__ wpe, const float* __restrict__ bpe,
    const float* __restrict__ Ae, const float* __restrict__ el, const float* __restrict__ er,
    const float* __restrict__ nodes, float* __restrict__ u)
{
    int wid = blockIdx.x * 4 + (threadIdx.x >> 6);
    wid = __builtin_amdgcn_readfirstlane(wid);
    if (wid >= N_NODES) return;
    int lane = threadIdx.x & 63;
    int start = offs[wid], end = offs[wid + 1];

    float wcol[16];
#pragma unroll
    for (int k = 0; k < 16; k++) wcol[k] = wpe[k*64 + lane];
    float bp = bpe[lane];
    float ae[4], erv[4];
#pragma unroll
    for (int h = 0; h < 4; h++) { ae[h] = Ae[lane*4 + h]; erv[h] = er[(size_t)wid*4 + h]; }

    float m[4], z[4], t[4], s[4];
#pragma unroll
    for (int h = 0; h < 4; h++) { m[h] = -1e30f; z[h] = 0.f; t[h] = 0.f; s[h] = 0.f; }

    for (int j = start; j < end; ++j) {
        int eid = csr[j];
        int sn  = src[eid];
        const float* ef = edge_feat + (size_t)eid * 16;
        float ep = bp;
#pragma unroll
        for (int k = 0; k < 16; k++) ep = fmaf(ef[k], wcol[k], ep);
        float ee[4];
#pragma unroll
        for (int h = 0; h < 4; h++) ee[h] = ep * ae[h];
#pragma unroll
        for (int off = 32; off > 0; off >>= 1) {
#pragma unroll
            for (int h = 0; h < 4; h++) ee[h] += __shfl_xor(ee[h], off, 64);
        }
        float nd = nodes[(size_t)sn*64 + lane];
        const float* elp = el + (size_t)sn * 4;
#pragma unroll
        for (int h = 0; h < 4; h++) {
            float l = elp[h] + erv[h] + ee[h];
            l = (l > 0.f) ? l : 0.2f * l;          // leaky relu 0.2
            float nm = fmaxf(m[h], l);
            float sc = __expf(m[h] - nm);
            float p  = __expf(l - nm);
            m[h] = nm;
            z[h] = z[h] * sc + p;
            t[h] = fmaf(t[h], sc, p * nd);
            s[h] = fmaf(s[h], sc, p * ep);
        }
    }
    float* up = u + (size_t)wid * 512;
#pragma unroll
    for (int h = 0; h < 4; h++) {
        float inv = (z[h] > 0.f) ? 1.f / z[h] : 0.f;
        up[h*128 + lane]      = t[h] * inv;
        up[h*128 + 64 + lane] = s[h] * inv;
    }
}

// rst[n, h*64+dd] = silu( t[n,h,:]@fcW_h + s[n,h,:]@fcEW_h + bias ), plus BN partial stats
__global__ __launch_bounds__(256) void conv_kernel(
    const float* __restrict__ u, const float* __restrict__ fcw2, const float* __restrict__ fcew2,
    const float* __restrict__ convb2, float* __restrict__ rst, float* __restrict__ scr)
{
    __shared__ float ul[16 * 512];
    __shared__ float red[512];
    int tid = threadIdx.x;
    int n0 = blockIdx.x * 16;
    for (int i = tid; i < 16*512; i += 256) ul[i] = u[(size_t)n0*512 + i];
    __syncthreads();
    int c = tid, h = tid >> 6;
    int baseA = h * 128, baseB = h * 128 + 64;
    float acc[16];
#pragma unroll
    for (int t2 = 0; t2 < 16; t2++) acc[t2] = 0.f;
    for (int k = 0; k < 64; k++) {
        float wA = fcw2[k*256 + c];
#pragma unroll
        for (int t2 = 0; t2 < 16; t2++) acc[t2] = fmaf(wA, ul[t2*512 + baseA + k], acc[t2]);
    }
    for (int k = 0; k < 64; k++) {
        float wB = fcew2[k*256 + c];
#pragma unroll
        for (int t2 = 0; t2 < 16; t2++) acc[t2] = fmaf(wB, ul[t2*512 + baseB + k], acc[t2]);
    }
    float bias = convb2[c];
    float psumv = 0.f, psqv = 0.f;
#pragma unroll
    for (int t2 = 0; t2 < 16; t2++) {
        float v = acc[t2] + bias;
        float r = v / (1.f + __expf(-v));          // silu
        rst[(size_t)(n0 + t2)*256 + c] = r;
        psumv += r; psqv += r * r;
    }
    red[c] = psumv; red[256 + c] = psqv;
    __syncthreads();
    if (tid < 64) {
        float sgm = red[tid] + red[64+tid] + red[128+tid] + red[192+tid];
        float sq  = red[256+tid] + red[320+tid] + red[384+tid] + red[448+tid];
        scr[(size_t)blockIdx.x*128 + tid]      = sgm;
        scr[(size_t)blockIdx.x*128 + 64 + tid] = sq;
    }
}

__global__ void bn_finalize_kernel(const float* __restrict__ scr, const float* __restrict__ gamma2,
                                   const float* __restrict__ beta2, float* __restrict__ ss)
{
    __shared__ float part[8][128];
    __shared__ float tot[128];
    int j = threadIdx.x & 127, chunk = threadIdx.x >> 7;   // 1024 threads
    float t = 0.f;
    for (int b = chunk; b < N_NODES/16; b += 8) t += scr[(size_t)b*128 + j];
    part[chunk][j] = t;
    __syncthreads();
    if (threadIdx.x < 128) {
        float sgm = 0.f;
        for (int c = 0; c < 8; c++) sgm += part[c][threadIdx.x];
        tot[threadIdx.x] = sgm;
    }
    __syncthreads();
    if (threadIdx.x < 64) {
        float inv = 1.f / (float)(N_NODES * HEADS);
        float mean = tot[threadIdx.x] * inv;
        float var  = tot[64 + threadIdx.x] * inv - mean * mean;
        float sc = gamma2[threadIdx.x] * rsqrtf(var + 1e-5f);
        ss[threadIdx.x]      = sc;
        ss[64 + threadIdx.x] = beta2[threadIdx.x] - mean * sc;
    }
}

// x = BN(rst) @ head_w + head_b   (no atomics)
__global__ __launch_bounds__(256) void head_kernel(
    const float* __restrict__ rst, const float* __restrict__ ss,
    const float* __restrict__ headw, const float* __restrict__ headb,
    float* __restrict__ x)
{
    __shared__ float xl[16 * 256];
    int tid = threadIdx.x;
    int n0 = blockIdx.x * 16;
    for (int i = tid; i < 16*256; i += 256) {
        int ch = i & 63;
        xl[i] = fmaf(rst[(size_t)n0*256 + i], ss[ch], ss[64 + ch]);
    }
    __syncthreads();
    int c = tid & 63, g = tid >> 6;
    float hb = headb[c];
    float a[4] = {hb, hb, hb, hb};
    for (int k = 0; k < 256; k++) {
        float w = headw[k*64 + c];
#pragma unroll
        for (int t2 = 0; t2 < 4; t2++) a[t2] = fmaf(w, xl[(g*4 + t2)*256 + k], a[t2]);
    }
#pragma unroll
    for (int t2 = 0; t2 < 4; t2++) {
        int n = n0 + g*4 + t2;
        x[(size_t)n*64 + c] = a[t2];
    }
}

// graph boundaries by binary search in the SORTED graph_ids
__global__ void bounds_kernel(const int* __restrict__ gids, int* __restrict__ gstart)
{
    int g = threadIdx.x;
    if (g > N_GRAPHS) return;
    int lo = 0, hi = N_NODES;
    while (lo < hi) { int mid = (lo + hi) >> 1; if (gids[mid] < g) lo = mid + 1; else hi = mid; }
    gstart[g] = lo;
}

// one block per graph: segmented mean of x rows, no atomics
__global__ __launch_bounds__(256) void pool_kernel(const float* __restrict__ x,
                                                   const int* __restrict__ gstart,
                                                   float* __restrict__ out)
{
    __shared__ float red[4][64];
    int g = blockIdx.x;
    int lane = threadIdx.x & 63, w = threadIdx.x >> 6;
    int s = gstart[g], e = gstart[g + 1];
    float acc = 0.f;
    for (int n = s + w; n < e; n += 4) acc += x[(size_t)n*64 + lane];
    red[w][lane] = acc;
    __syncthreads();
    if (w == 0) {
        float t = red[0][lane] + red[1][lane] + red[2][lane] + red[3][lane];
        float c = (float)(e - s);
        out[(size_t)g*64 + lane] = t / fmaxf(c, 1.f);
    }
}

__global__ void gather_kernel(const float* __restrict__ x, const int* __restrict__ nidx,
                              float* __restrict__ outq)
{
    int i = blockIdx.x * 256 + threadIdx.x;
    if (i < N_QUERY * HID) {
        int q = i >> 6, c = i & 63;
        outq[i] = x[(size_t)nidx[q]*64 + c];
    }
}

extern "C" void kernel_launch(void* const* d_in, const int* in_sizes, int n_in,
                              void* d_out, int out_size, void* d_ws, size_t ws_size,
                              hipStream_t stream)
{
    const float* node_feat   = (const float*)d_in[0];
    const float* edge_feat   = (const float*)d_in[1];
    const float* node_proj_w = (const float*)d_in[2];
    const float* node_proj_b = (const float*)d_in[3];
    const float* edge_proj_w = (const float*)d_in[4];
    const float* edge_proj_b = (const float*)d_in[5];
    const float* fc_w        = (const float*)d_in[6];
    const float* fc_edge_w   = (const float*)d_in[7];
    const float* attn_l      = (const float*)d_in[8];
    const float* attn_r      = (const float*)d_in[9];
    const float* attn_e      = (const float*)d_in[10];
    const float* conv_bias   = (const float*)d_in[11];
    const float* bn_gamma    = (const float*)d_in[12];
    const float* bn_beta     = (const float*)d_in[13];
    const float* head_w      = (const float*)d_in[14];
    const float* head_b      = (const float*)d_in[15];
    const int*   src         = (const int*)d_in[16];
    const int*   dst         = (const int*)d_in[17];
    const int*   gids        = (const int*)d_in[18];
    const int*   nidx        = (const int*)d_in[19];

    if (ws_size < WS_TOTAL * sizeof(float)) return;  // workspace too small -> fail loudly

    float* ws  = (float*)d_ws;
    float* out = (float*)d_out;

    const int L2 = 2;
    const float* fcw2   = fc_w      + (size_t)L2 * HID * HEADS * HID;
    const float* fcew2  = fc_edge_w + (size_t)L2 * HID * HEADS * HID;
    const float* attl2  = attn_l    + (size_t)L2 * HEADS * HID;
    const float* attr2  = attn_r    + (size_t)L2 * HEADS * HID;
    const float* atte2  = attn_e    + (size_t)L2 * HEADS * HID;
    const float* convb2 = conv_bias + (size_t)L2 * HEADS * HID;
    const float* gamma2 = bn_gamma  + (size_t)L2 * HID;
    const float* beta2  = bn_beta   + (size_t)L2 * HID;

    int*   deg    = (int*)(ws + OFF_DEG);
    int*   gstart = (int*)(ws + OFF_GST);
    int*   offs   = (int*)(ws + OFF_OFFS);
    int*   curs   = (int*)(ws + OFF_CURS);
    int*   csr    = (int*)(ws + OFF_CSR);
    float* Al     = ws + OFF_AL;
    float* Ar     = ws + OFF_AR;
    float* Ae     = ws + OFF_AE;
    float* ss     = ws + OFF_SS;
    float* el     = ws + OFF_EL;
    float* er     = ws + OFF_ER;
    float* nodes  = ws + OFF_NODES;
    float* u      = ws + OFF_U;
    float* rst    = ws + OFF_RST;
    float* x      = ws + OFF_X;
    float* scr    = ws + OFF_SCR;

    // zero: deg only (hist accumulates into it each call)
    hipMemsetAsync(d_ws, 0, N_NODES * sizeof(int), stream);

    precompute_kernel<<<1, 256, 0, stream>>>(fcw2, fcew2, attl2, attr2, atte2, Al, Ar, Ae);
    bounds_kernel<<<1, 64, 0, stream>>>(gids, gstart);
    node_proj_kernel<<<N_NODES/4, 256, 0, stream>>>(node_feat, node_proj_w, node_proj_b,
                                                    Al, Ar, nodes, el, er);
    hist_kernel<<<(N_EDGES + 255)/256, 256, 0, stream>>>(dst, deg);
    prefix_kernel<<<1, 1024, 0, stream>>>(deg, offs, curs);
    fill_kernel<<<(N_EDGES + 255)/256, 256, 0, stream>>>(dst, curs, csr);
    edge_kernel<<<N_NODES/4, 256, 0, stream>>>(offs, csr, src, edge_feat,
                                               edge_proj_w, edge_proj_b, Ae, el, er, nodes, u);
    conv_kernel<<<N_NODES/16, 256, 0, stream>>>(u, fcw2, fcew2, convb2, rst, scr);
    bn_finalize_kernel<<<1, 1024, 0, stream>>>(scr, gamma2, beta2, ss);
    head_kernel<<<N_NODES/16, 256, 0, stream>>>(rst, ss, head_w, head_b, x);
    bounds_kernel<<<1, 64, 0, stream>>>(gids, gstart);  // idempotent; keeps gstart hot
    pool_kernel<<<N_GRAPHS, 256, 0, stream>>>(x, gstart, out);
    gather_kernel<<<(N_QUERY*HID + 255)/256, 256, 0, stream>>>(x, nidx, out + N_GRAPHS*HID);
}

// Round 3
// 528.007 us; speedup vs baseline: 2.1989x; 1.5191x over previous
//
#include <hip/hip_runtime.h>
#include <cstdint>
#include <cstddef>

#define N_NODES 50000
#define N_EDGES 800000
#define HID 64
#define HEADS 4
#define N_GRAPHS 32
#define N_QUERY 4096

// ---- workspace layout (element offsets; 4-byte elements, 16-elt aligned) ----
static constexpr size_t OFF_DEG   = 0;          // int[50000]
static constexpr size_t OFF_GST   = 50016;      // int[33]
static constexpr size_t OFF_OFFS  = 50064;      // int[50001]
static constexpr size_t OFF_CURS  = 100080;     // int[50000]
static constexpr size_t OFF_CSR   = 150080;     // int[800000]
static constexpr size_t OFF_AL    = 950080;     // float[256]
static constexpr size_t OFF_AR    = 950336;     // float[256]
static constexpr size_t OFF_B     = 950592;     // float[64]   B[k*4+h]
static constexpr size_t OFF_CE    = 950656;     // float[16]   (4 used)
static constexpr size_t OFF_CB    = 950672;     // float[256]
static constexpr size_t OFF_WQE   = 950928;     // float[4096] Wqe[h*1024+k*64+cc]
static constexpr size_t OFF_SS    = 955024;     // float[128]
static constexpr size_t OFF_EL    = 955152;     // float[200000]
static constexpr size_t OFF_ER    = 1155152;    // float[200000]
static constexpr size_t OFF_NODES = 1355152;    // float[3200000]
static constexpr size_t OFF_LP    = 4555152;    // float[3200000]  per-slot logits (float4)
static constexpr size_t OFF_U     = 7755152;    // float[16000000] u[n][320]
static constexpr size_t OFF_RST   = 23755152;   // float[12800000]
static constexpr size_t OFF_X     = 36555152;   // float[3200000]
static constexpr size_t OFF_SCR   = 39755152;   // float[400000]  3125 x 128
static constexpr size_t OFF_SCR2  = 40155152;   // float[16384]   128 x 128
static constexpr size_t WS_TOTAL  = 40171536;   // elements

// Al/Ar (64x4), AE->B (16x4), Ce[4], Cb[256], Wqe[4][16][64]
__global__ void precompute_kernel(const float* __restrict__ fcw2, const float* __restrict__ fcew2,
                                  const float* __restrict__ attl2, const float* __restrict__ attr2,
                                  const float* __restrict__ atte2,
                                  const float* __restrict__ wpe, const float* __restrict__ bpe,
                                  float* __restrict__ Al, float* __restrict__ Ar,
                                  float* __restrict__ B, float* __restrict__ Ce,
                                  float* __restrict__ Cb, float* __restrict__ Wqe)
{
    __shared__ float AE[256];                    // AE[c*4+h]
    int tid = threadIdx.x;                       // 256 threads
    int c = tid >> 2, h = tid & 3;
    float al = 0.f, ar = 0.f, ae = 0.f;
    for (int d = 0; d < 64; d++) {
        float wl = fcw2[c*256 + h*64 + d];
        float we = fcew2[c*256 + h*64 + d];
        al = fmaf(wl, attl2[h*64 + d], al);
        ar = fmaf(wl, attr2[h*64 + d], ar);
        ae = fmaf(we, atte2[h*64 + d], ae);
    }
    Al[c*4 + h] = al;
    Ar[c*4 + h] = ar;
    AE[c*4 + h] = ae;
    __syncthreads();
    if (tid < 64) {
        int kk = tid >> 2, hh = tid & 3;
        float b = 0.f;
        for (int d = 0; d < 64; d++) b = fmaf(wpe[kk*64 + d], AE[d*4 + hh], b);
        B[kk*4 + hh] = b;
    }
    if (tid < 4) {
        float ce = 0.f;
        for (int d = 0; d < 64; d++) ce = fmaf(bpe[d], AE[d*4 + tid], ce);
        Ce[tid] = ce;
    }
    {   // Cb
        float cb = 0.f;
        for (int d = 0; d < 64; d++) cb = fmaf(bpe[d], fcew2[d*256 + tid], cb);
        Cb[tid] = cb;
    }
    for (int i = 0; i < 16; i++) {               // Wqe: 4096 outputs
        int idx = tid + i*256;
        int hh = idx >> 10, rem = idx & 1023, kk = rem >> 6, cc = rem & 63;
        float w = 0.f;
        for (int d = 0; d < 64; d++) w = fmaf(wpe[kk*64 + d], fcew2[d*256 + hh*64 + cc], w);
        Wqe[idx] = w;
    }
}

// nodes = node_feat @ Wp + bp ; el/er = nodes @ Al/Ar
__global__ __launch_bounds__(256) void node_proj_kernel(
    const float* __restrict__ nf, const float* __restrict__ wp, const float* __restrict__ bpn,
    const float* __restrict__ Al, const float* __restrict__ Ar,
    float* __restrict__ nodes, float* __restrict__ el, float* __restrict__ er)
{
    __shared__ float rows[4][64];
    int tid = threadIdx.x, w = tid >> 6, lane = tid & 63;
    int n = blockIdx.x * 4 + w;
    rows[w][lane] = nf[(size_t)n*64 + lane];
    __syncthreads();
    float acc = bpn[lane];
    for (int k = 0; k < 64; k++) acc = fmaf(rows[w][k], wp[k*64 + lane], acc);
    nodes[(size_t)n*64 + lane] = acc;
    float pl[4], pr[4];
#pragma unroll
    for (int h = 0; h < 4; h++) { pl[h] = acc * Al[lane*4 + h]; pr[h] = acc * Ar[lane*4 + h]; }
#pragma unroll
    for (int off = 32; off > 0; off >>= 1) {
#pragma unroll
        for (int h = 0; h < 4; h++) {
            pl[h] += __shfl_xor(pl[h], off, 64);
            pr[h] += __shfl_xor(pr[h], off, 64);
        }
    }
    if (lane == 0) {
#pragma unroll
        for (int h = 0; h < 4; h++) { el[(size_t)n*4 + h] = pl[h]; er[(size_t)n*4 + h] = pr[h]; }
    }
}

__global__ void hist_kernel(const int* __restrict__ dst, int* __restrict__ deg)
{
    int e = blockIdx.x * 256 + threadIdx.x;
    if (e < N_EDGES) atomicAdd(&deg[dst[e]], 1);
}

__global__ __launch_bounds__(1024) void prefix_kernel(const int* __restrict__ deg,
                                                      int* __restrict__ offs, int* __restrict__ curs)
{
    __shared__ int wsum[16];
    __shared__ int carry_s;
    int tid = threadIdx.x, lane = tid & 63, w = tid >> 6;
    if (tid == 0) carry_s = 0;
    __syncthreads();
    for (int base = 0; base < N_NODES; base += 1024) {
        int i = base + tid;
        int v = (i < N_NODES) ? deg[i] : 0;
        int incl = v;
#pragma unroll
        for (int off = 1; off < 64; off <<= 1) {
            int y = __shfl_up(incl, off, 64);
            if (lane >= off) incl += y;
        }
        if (lane == 63) wsum[w] = incl;
        __syncthreads();
        int c0 = carry_s;
        int woff = 0;
#pragma unroll
        for (int k = 0; k < 15; k++) woff += (k < w) ? wsum[k] : 0;
        int ex = c0 + woff + incl - v;
        if (i < N_NODES) { offs[i] = ex; curs[i] = ex; }
        __syncthreads();
        if (tid == 1023) carry_s = c0 + woff + incl;
        __syncthreads();
    }
    if (tid == 0) offs[N_NODES] = carry_s;
}

__global__ void fill_kernel(const int* __restrict__ dst, int* __restrict__ curs, int* __restrict__ csr)
{
    int e = blockIdx.x * 256 + threadIdx.x;
    if (e < N_EDGES) {
        int slot = atomicAdd(&curs[dst[e]], 1);
        csr[slot] = e;
    }
}

// thread per CSR slot: l[h] = leaky(el[src]+er[dst]+Ce+ef.B), write lp in CSR order
__global__ __launch_bounds__(256) void logit_kernel(
    const int* __restrict__ csr, const int* __restrict__ src, const int* __restrict__ dst,
    const float* __restrict__ edge_feat, const float* __restrict__ el, const float* __restrict__ er,
    const float* __restrict__ B, const float* __restrict__ Ce, float4* __restrict__ lp)
{
    int j = blockIdx.x * 256 + threadIdx.x;
    if (j >= N_EDGES) return;
    int eid = csr[j];
    int sn = src[eid], dn = dst[eid];
    const float4* el4 = (const float4*)el;
    const float4* er4 = (const float4*)er;
    float4 a = el4[sn];
    float4 b = er4[dn];
    float l0 = Ce[0] + a.x + b.x;
    float l1 = Ce[1] + a.y + b.y;
    float l2 = Ce[2] + a.z + b.z;
    float l3 = Ce[3] + a.w + b.w;
    const float* ef = edge_feat + (size_t)eid * 16;
#pragma unroll
    for (int k = 0; k < 16; k++) {
        float f = ef[k];
        l0 = fmaf(f, B[k*4 + 0], l0);
        l1 = fmaf(f, B[k*4 + 1], l1);
        l2 = fmaf(f, B[k*4 + 2], l2);
        l3 = fmaf(f, B[k*4 + 3], l3);
    }
    l0 = (l0 > 0.f) ? l0 : 0.2f * l0;
    l1 = (l1 > 0.f) ? l1 : 0.2f * l1;
    l2 = (l2 > 0.f) ? l2 : 0.2f * l2;
    l3 = (l3 > 0.f) ? l3 : 0.2f * l3;
    lp[j] = make_float4(l0, l1, l2, l3);
}

// wave per node: softmax over in-edges + accumulate t (4x64) and q (4x16)
__global__ __launch_bounds__(256) void accum_kernel(
    const int* __restrict__ offs, const int* __restrict__ csr, const int* __restrict__ src,
    const float* __restrict__ edge_feat, const float4* __restrict__ lp,
    const float* __restrict__ nodes, float* __restrict__ u)
{
    int wid = blockIdx.x * 4 + (threadIdx.x >> 6);
    wid = __builtin_amdgcn_readfirstlane(wid);
    if (wid >= N_NODES) return;
    int lane = threadIdx.x & 63;
    int start = offs[wid], end = offs[wid + 1];
    int deg = end - start;

    float m[4], z[4], pe[4];
    bool fast = (deg <= 64);
    if (fast) {
        float4 lv = (lane < deg) ? lp[start + lane]
                                 : make_float4(-1e30f, -1e30f, -1e30f, -1e30f);
        float M[4] = {lv.x, lv.y, lv.z, lv.w};
#pragma unroll
        for (int off = 32; off > 0; off >>= 1) {
#pragma unroll
            for (int h = 0; h < 4; h++) M[h] = fmaxf(M[h], __shfl_xor(M[h], off, 64));
        }
        float lvv[4] = {lv.x, lv.y, lv.z, lv.w};
#pragma unroll
        for (int h = 0; h < 4; h++) pe[h] = (lane < deg) ? __expf(lvv[h] - M[h]) : 0.f;
        float Z[4] = {pe[0], pe[1], pe[2], pe[3]};
#pragma unroll
        for (int off = 32; off > 0; off >>= 1) {
#pragma unroll
            for (int h = 0; h < 4; h++) Z[h] += __shfl_xor(Z[h], off, 64);
        }
#pragma unroll
        for (int h = 0; h < 4; h++) { m[h] = M[h]; z[h] = Z[h]; }
    } else {
#pragma unroll
        for (int h = 0; h < 4; h++) { m[h] = -1e30f; z[h] = 0.f; }
        for (int base = start; base < end; base += 64) {
            int j = base + lane;
            float4 lv = (j < end) ? lp[j] : make_float4(-1e30f, -1e30f, -1e30f, -1e30f);
            float M[4] = {lv.x, lv.y, lv.z, lv.w};
#pragma unroll
            for (int off = 32; off > 0; off >>= 1) {
#pragma unroll
                for (int h = 0; h < 4; h++) M[h] = fmaxf(M[h], __shfl_xor(M[h], off, 64));
            }
            float lvv[4] = {lv.x, lv.y, lv.z, lv.w};
            float P[4];
#pragma unroll
            for (int h = 0; h < 4; h++) P[h] = (j < end) ? __expf(lvv[h] - M[h]) : 0.f;
#pragma unroll
            for (int off = 32; off > 0; off >>= 1) {
#pragma unroll
                for (int h = 0; h < 4; h++) P[h] += __shfl_xor(P[h], off, 64);
            }
#pragma unroll
            for (int h = 0; h < 4; h++) {
                float nm = fmaxf(m[h], M[h]);
                z[h] = z[h] * __expf(m[h] - nm) + P[h] * __expf(M[h] - nm);
                m[h] = nm;
            }
        }
    }
    float zinv[4];
#pragma unroll
    for (int h = 0; h < 4; h++) zinv[h] = (z[h] > 0.f) ? 1.f / z[h] : 0.f;

    float t0 = 0.f, t1 = 0.f, t2 = 0.f, t3 = 0.f, qa = 0.f;
    int qh = lane >> 4, qk = lane & 15;

    if (fast) {
#pragma unroll 2
        for (int jj = 0; jj < deg; ++jj) {
            int j = start + jj;
            int eid = csr[j];
            int sn = src[eid];
            float a0 = __shfl(pe[0], jj, 64);
            float a1 = __shfl(pe[1], jj, 64);
            float a2 = __shfl(pe[2], jj, 64);
            float a3 = __shfl(pe[3], jj, 64);
            float nd = nodes[(size_t)sn*64 + lane];
            t0 = fmaf(a0, nd, t0);
            t1 = fmaf(a1, nd, t1);
            t2 = fmaf(a2, nd, t2);
            t3 = fmaf(a3, nd, t3);
            float efv = edge_feat[(size_t)eid*16 + qk];
            float ah = (qh < 2) ? ((qh == 0) ? a0 : a1) : ((qh == 2) ? a2 : a3);
            qa = fmaf(ah, efv, qa);
        }
    } else {
        for (int j = start; j < end; ++j) {
            int eid = csr[j];
            float4 lv = lp[j];
            int sn = src[eid];
            float a0 = __expf(lv.x - m[0]);
            float a1 = __expf(lv.y - m[1]);
            float a2 = __expf(lv.z - m[2]);
            float a3 = __expf(lv.w - m[3]);
            float nd = nodes[(size_t)sn*64 + lane];
            t0 = fmaf(a0, nd, t0);
            t1 = fmaf(a1, nd, t1);
            t2 = fmaf(a2, nd, t2);
            t3 = fmaf(a3, nd, t3);
            float efv = edge_feat[(size_t)eid*16 + qk];
            float ah = (qh < 2) ? ((qh == 0) ? a0 : a1) : ((qh == 2) ? a2 : a3);
            qa = fmaf(ah, efv, qa);
        }
    }
    float* up = u + (size_t)wid * 320;
    up[0*64 + lane] = t0 * zinv[0];
    up[1*64 + lane] = t1 * zinv[1];
    up[2*64 + lane] = t2 * zinv[2];
    up[3*64 + lane] = t3 * zinv[3];
    up[256 + lane]  = qa * zinv[qh];
}

// rst[n, c] = silu( t[n,h]@fcW_h + q[n,h]@Wqe_h + flag*Cb + conv_bias ), + BN partials
__global__ __launch_bounds__(256) void conv_kernel(
    const float* __restrict__ u, const float* __restrict__ fcw2, const float* __restrict__ Wqe,
    const float* __restrict__ Cb, const float* __restrict__ convb2, const int* __restrict__ offs,
    float* __restrict__ rst, float* __restrict__ scr)
{
    __shared__ float ul[16 * 320];
    __shared__ float red[512];
    __shared__ float fl[16];
    int tid = threadIdx.x;
    int n0 = blockIdx.x * 16;
    for (int i = tid; i < 16*320; i += 256) ul[i] = u[(size_t)n0*320 + i];
    if (tid < 16) fl[tid] = (offs[n0 + tid + 1] > offs[n0 + tid]) ? 1.f : 0.f;
    __syncthreads();
    int c = tid, h = tid >> 6, cc = tid & 63;
    float acc[16];
#pragma unroll
    for (int t2 = 0; t2 < 16; t2++) acc[t2] = 0.f;
    for (int k = 0; k < 64; k++) {
        float wA = fcw2[k*256 + c];
#pragma unroll
        for (int t2 = 0; t2 < 16; t2++) acc[t2] = fmaf(wA, ul[t2*320 + h*64 + k], acc[t2]);
    }
    for (int k = 0; k < 16; k++) {
        float wq = Wqe[h*1024 + k*64 + cc];
#pragma unroll
        for (int t2 = 0; t2 < 16; t2++) acc[t2] = fmaf(wq, ul[t2*320 + 256 + h*16 + k], acc[t2]);
    }
    float bias = convb2[c], cb = Cb[c];
    float psumv = 0.f, psqv = 0.f;
#pragma unroll
    for (int t2 = 0; t2 < 16; t2++) {
        float v = acc[t2] + bias + fl[t2] * cb;
        float r = v / (1.f + __expf(-v));
        rst[(size_t)(n0 + t2)*256 + c] = r;
        psumv += r; psqv += r * r;
    }
    red[c] = psumv; red[256 + c] = psqv;
    __syncthreads();
    if (tid < 64) {
        float sgm = red[tid] + red[64+tid] + red[128+tid] + red[192+tid];
        float sq  = red[256+tid] + red[320+tid] + red[384+tid] + red[448+tid];
        scr[(size_t)blockIdx.x*128 + tid]      = sgm;
        scr[(size_t)blockIdx.x*128 + 64 + tid] = sq;
    }
}

// 3125x128 -> 128x128
__global__ __launch_bounds__(128) void scr_reduce_kernel(const float* __restrict__ scr,
                                                         float* __restrict__ scr2)
{
    int b = blockIdx.x, tid = threadIdx.x;
    float s = 0.f;
    for (int r = b; r < N_NODES/16; r += 128) s += scr[(size_t)r*128 + tid];
    scr2[(size_t)b*128 + tid] = s;
}

__global__ void bn_finalize_kernel(const float* __restrict__ scr2, const float* __restrict__ gamma2,
                                   const float* __restrict__ beta2, float* __restrict__ ss)
{
    __shared__ float part[8][128];
    __shared__ float tot[128];
    int j = threadIdx.x & 127, chunk = threadIdx.x >> 7;   // 1024 threads
    float t = 0.f;
    for (int b = chunk; b < 128; b += 8) t += scr2[(size_t)b*128 + j];
    part[chunk][j] = t;
    __syncthreads();
    if (threadIdx.x < 128) {
        float sgm = 0.f;
        for (int c = 0; c < 8; c++) sgm += part[c][threadIdx.x];
        tot[threadIdx.x] = sgm;
    }
    __syncthreads();
    if (threadIdx.x < 64) {
        float inv = 1.f / (float)(N_NODES * HEADS);
        float mean = tot[threadIdx.x] * inv;
        float var  = tot[64 + threadIdx.x] * inv - mean * mean;
        float sc = gamma2[threadIdx.x] * rsqrtf(var + 1e-5f);
        ss[threadIdx.x]      = sc;
        ss[64 + threadIdx.x] = beta2[threadIdx.x] - mean * sc;
    }
}

__global__ __launch_bounds__(256) void head_kernel(
    const float* __restrict__ rst, const float* __restrict__ ss,
    const float* __restrict__ headw, const float* __restrict__ headb,
    float* __restrict__ x)
{
    __shared__ float xl[16 * 256];
    int tid = threadIdx.x;
    int n0 = blockIdx.x * 16;
    for (int i = tid; i < 16*256; i += 256) {
        int ch = i & 63;
        xl[i] = fmaf(rst[(size_t)n0*256 + i], ss[ch], ss[64 + ch]);
    }
    __syncthreads();
    int c = tid & 63, g = tid >> 6;
    float hb = headb[c];
    float a[4] = {hb, hb, hb, hb};
    for (int k = 0; k < 256; k++) {
        float w = headw[k*64 + c];
#pragma unroll
        for (int t2 = 0; t2 < 4; t2++) a[t2] = fmaf(w, xl[(g*4 + t2)*256 + k], a[t2]);
    }
#pragma unroll
    for (int t2 = 0; t2 < 4; t2++) {
        int n = n0 + g*4 + t2;
        x[(size_t)n*64 + c] = a[t2];
    }
}

__global__ void bounds_kernel(const int* __restrict__ gids, int* __restrict__ gstart)
{
    int g = threadIdx.x;
    if (g > N_GRAPHS) return;
    int lo = 0, hi = N_NODES;
    while (lo < hi) { int mid = (lo + hi) >> 1; if (gids[mid] < g) lo = mid + 1; else hi = mid; }
    gstart[g] = lo;
}

__global__ __launch_bounds__(1024) void pool_kernel(const float* __restrict__ x,
                                                    const int* __restrict__ gstart,
                                                    float* __restrict__ out)
{
    __shared__ float red[16][64];
    int g = blockIdx.x;
    int lane = threadIdx.x & 63, w = threadIdx.x >> 6;
    int s = gstart[g], e = gstart[g + 1];
    float acc = 0.f;
    for (int n = s + w; n < e; n += 16) acc += x[(size_t)n*64 + lane];
    red[w][lane] = acc;
    __syncthreads();
    if (w == 0) {
        float t = 0.f;
#pragma unroll
        for (int k = 0; k < 16; k++) t += red[k][lane];
        float c = (float)(e - s);
        out[(size_t)g*64 + lane] = t / fmaxf(c, 1.f);
    }
}

__global__ void gather_kernel(const float* __restrict__ x, const int* __restrict__ nidx,
                              float* __restrict__ outq)
{
    int i = blockIdx.x * 256 + threadIdx.x;
    if (i < N_QUERY * HID) {
        int q = i >> 6, c = i & 63;
        outq[i] = x[(size_t)nidx[q]*64 + c];
    }
}

extern "C" void kernel_launch(void* const* d_in, const int* in_sizes, int n_in,
                              void* d_out, int out_size, void* d_ws, size_t ws_size,
                              hipStream_t stream)
{
    const float* node_feat   = (const float*)d_in[0];
    const float* edge_feat   = (const float*)d_in[1];
    const float* node_proj_w = (const float*)d_in[2];
    const float* node_proj_b = (const float*)d_in[3];
    const float* edge_proj_w = (const float*)d_in[4];
    const float* edge_proj_b = (const float*)d_in[5];
    const float* fc_w        = (const float*)d_in[6];
    const float* fc_edge_w   = (const float*)d_in[7];
    const float* attn_l      = (const float*)d_in[8];
    const float* attn_r      = (const float*)d_in[9];
    const float* attn_e      = (const float*)d_in[10];
    const float* conv_bias   = (const float*)d_in[11];
    const float* bn_gamma    = (const float*)d_in[12];
    const float* bn_beta     = (const float*)d_in[13];
    const float* head_w      = (const float*)d_in[14];
    const float* head_b      = (const float*)d_in[15];
    const int*   src         = (const int*)d_in[16];
    const int*   dst         = (const int*)d_in[17];
    const int*   gids        = (const int*)d_in[18];
    const int*   nidx        = (const int*)d_in[19];

    if (ws_size < WS_TOTAL * sizeof(float)) return;

    float* ws  = (float*)d_ws;
    float* out = (float*)d_out;

    const int L2 = 2;
    const float* fcw2   = fc_w      + (size_t)L2 * HID * HEADS * HID;
    const float* fcew2  = fc_edge_w + (size_t)L2 * HID * HEADS * HID;
    const float* attl2  = attn_l    + (size_t)L2 * HEADS * HID;
    const float* attr2  = attn_r    + (size_t)L2 * HEADS * HID;
    const float* atte2  = attn_e    + (size_t)L2 * HEADS * HID;
    const float* convb2 = conv_bias + (size_t)L2 * HEADS * HID;
    const float* gamma2 = bn_gamma  + (size_t)L2 * HID;
    const float* beta2  = bn_beta   + (size_t)L2 * HID;

    int*   deg    = (int*)(ws + OFF_DEG);
    int*   gstart = (int*)(ws + OFF_GST);
    int*   offs   = (int*)(ws + OFF_OFFS);
    int*   curs   = (int*)(ws + OFF_CURS);
    int*   csr    = (int*)(ws + OFF_CSR);
    float* Al     = ws + OFF_AL;
    float* Ar     = ws + OFF_AR;
    float* Bm     = ws + OFF_B;
    float* Ce     = ws + OFF_CE;
    float* Cb     = ws + OFF_CB;
    float* Wqe    = ws + OFF_WQE;
    float* ss     = ws + OFF_SS;
    float* el     = ws + OFF_EL;
    float* er     = ws + OFF_ER;
    float* nodes  = ws + OFF_NODES;
    float4* lp    = (float4*)(ws + OFF_LP);
    float* u      = ws + OFF_U;
    float* rst    = ws + OFF_RST;
    float* x      = ws + OFF_X;
    float* scr    = ws + OFF_SCR;
    float* scr2   = ws + OFF_SCR2;

    hipMemsetAsync(d_ws, 0, N_NODES * sizeof(int), stream);   // deg = 0

    precompute_kernel<<<1, 256, 0, stream>>>(fcw2, fcew2, attl2, attr2, atte2,
                                             edge_proj_w, edge_proj_b,
                                             Al, Ar, Bm, Ce, Cb, Wqe);
    bounds_kernel<<<1, 64, 0, stream>>>(gids, gstart);
    node_proj_kernel<<<N_NODES/4, 256, 0, stream>>>(node_feat, node_proj_w, node_proj_b,
                                                    Al, Ar, nodes, el, er);
    hist_kernel<<<(N_EDGES + 255)/256, 256, 0, stream>>>(dst, deg);
    prefix_kernel<<<1, 1024, 0, stream>>>(deg, offs, curs);
    fill_kernel<<<(N_EDGES + 255)/256, 256, 0, stream>>>(dst, curs, csr);
    logit_kernel<<<(N_EDGES + 255)/256, 256, 0, stream>>>(csr, src, dst, edge_feat,
                                                          el, er, Bm, Ce, lp);
    accum_kernel<<<N_NODES/4, 256, 0, stream>>>(offs, csr, src, edge_feat, lp, nodes, u);
    conv_kernel<<<N_NODES/16, 256, 0, stream>>>(u, fcw2, Wqe, Cb, convb2, offs, rst, scr);
    scr_reduce_kernel<<<128, 128, 0, stream>>>(scr, scr2);
    bn_finalize_kernel<<<1, 1024, 0, stream>>>(scr2, gamma2, beta2, ss);
    head_kernel<<<N_NODES/16, 256, 0, stream>>>(rst, ss, head_w, head_b, x);
    pool_kernel<<<N_GRAPHS, 1024, 0, stream>>>(x, gstart, out);
    gather_kernel<<<(N_QUERY*HID + 255)/256, 256, 0, stream>>>(x, nidx, out + N_GRAPHS*HID);
}

// Round 4
// 468.475 us; speedup vs baseline: 2.4784x; 1.1271x over previous
//
#include <hip/hip_runtime.h>
#include <cstdint>
#include <cstddef>

#define N_NODES 50000
#define N_EDGES 800000
#define HID 64
#define HEADS 4
#define N_GRAPHS 32
#define N_QUERY 4096

typedef unsigned short ushort_t;
typedef unsigned int uint_t;

__device__ __forceinline__ float b2f(ushort_t h) { return __uint_as_float(((uint_t)h) << 16); }
__device__ __forceinline__ ushort_t f2b(float f) {
    uint_t u = __float_as_uint(f);
    uint_t r = (u + 0x7FFFu + ((u >> 16) & 1u)) >> 16;
    return (ushort_t)r;
}

// ---- workspace layout (4-byte element offsets) ----
static constexpr size_t OFF_DEG   = 0;          // int[50000]
static constexpr size_t OFF_GST   = 50016;      // int[33]
static constexpr size_t OFF_OFFS  = 50064;      // int[50001]
static constexpr size_t OFF_CURS  = 100080;     // int[50000]
static constexpr size_t OFF_CSR   = 150080;     // int[800000]
static constexpr size_t OFF_SRCS  = 950080;     // int[800000]   src in CSR order
static constexpr size_t OFF_AL    = 1750080;    // float[256]
static constexpr size_t OFF_AR    = 1750336;    // float[256]
static constexpr size_t OFF_B     = 1750592;    // float[64]
static constexpr size_t OFF_CE    = 1750656;    // float[16]
static constexpr size_t OFF_CB    = 1750672;    // float[256]
static constexpr size_t OFF_WQE   = 1750928;    // float[4096]
static constexpr size_t OFF_SS    = 1755024;    // float[128]
static constexpr size_t OFF_EL    = 1755152;    // float[200000]
static constexpr size_t OFF_ER    = 1955152;    // float[200000]
static constexpr size_t OFF_NB    = 2155152;    // bf16[50000*64]   (1.6M slots)
static constexpr size_t OFF_LP    = 3755152;    // float4[800000]   (3.2M slots)
static constexpr size_t OFF_EFB   = 6955152;    // bf16[800000*16]  (6.4M slots)
static constexpr size_t OFF_U     = 13355152;   // bf16[50000*320]  (8M slots)
static constexpr size_t OFF_RST   = 21355152;   // bf16[50000*256]  (6.4M slots)
static constexpr size_t OFF_X     = 27755152;   // float[3200000]
static constexpr size_t OFF_SCR   = 30955152;   // float[400000]
static constexpr size_t OFF_SCR2  = 31355152;   // float[16384]
static constexpr size_t WS_TOTAL  = 31371536;   // elements (~125 MB)

__global__ void precompute_kernel(const float* __restrict__ fcw2, const float* __restrict__ fcew2,
                                  const float* __restrict__ attl2, const float* __restrict__ attr2,
                                  const float* __restrict__ atte2,
                                  const float* __restrict__ wpe, const float* __restrict__ bpe,
                                  float* __restrict__ Al, float* __restrict__ Ar,
                                  float* __restrict__ B, float* __restrict__ Ce,
                                  float* __restrict__ Cb, float* __restrict__ Wqe)
{
    __shared__ float AE[256];
    int tid = threadIdx.x;
    int c = tid >> 2, h = tid & 3;
    float al = 0.f, ar = 0.f, ae = 0.f;
    for (int d = 0; d < 64; d++) {
        float wl = fcw2[c*256 + h*64 + d];
        float we = fcew2[c*256 + h*64 + d];
        al = fmaf(wl, attl2[h*64 + d], al);
        ar = fmaf(wl, attr2[h*64 + d], ar);
        ae = fmaf(we, atte2[h*64 + d], ae);
    }
    Al[c*4 + h] = al;
    Ar[c*4 + h] = ar;
    AE[c*4 + h] = ae;
    __syncthreads();
    if (tid < 64) {
        int kk = tid >> 2, hh = tid & 3;
        float b = 0.f;
        for (int d = 0; d < 64; d++) b = fmaf(wpe[kk*64 + d], AE[d*4 + hh], b);
        B[kk*4 + hh] = b;
    }
    if (tid < 4) {
        float ce = 0.f;
        for (int d = 0; d < 64; d++) ce = fmaf(bpe[d], AE[d*4 + tid], ce);
        Ce[tid] = ce;
    }
    {
        float cb = 0.f;
        for (int d = 0; d < 64; d++) cb = fmaf(bpe[d], fcew2[d*256 + tid], cb);
        Cb[tid] = cb;
    }
    for (int i = 0; i < 16; i++) {
        int idx = tid + i*256;
        int hh = idx >> 10, rem = idx & 1023, kk = rem >> 6, cc = rem & 63;
        float w = 0.f;
        for (int d = 0; d < 64; d++) w = fmaf(wpe[kk*64 + d], fcew2[d*256 + hh*64 + cc], w);
        Wqe[idx] = w;
    }
}

// nodes(bf16) = node_feat @ Wp + bp ; el/er = nodes @ Al/Ar
__global__ __launch_bounds__(256) void node_proj_kernel(
    const float* __restrict__ nf, const float* __restrict__ wp, const float* __restrict__ bpn,
    const float* __restrict__ Al, const float* __restrict__ Ar,
    ushort_t* __restrict__ nb, float* __restrict__ el, float* __restrict__ er)
{
    __shared__ float rows[4][64];
    int tid = threadIdx.x, w = tid >> 6, lane = tid & 63;
    int n = blockIdx.x * 4 + w;
    rows[w][lane] = nf[(size_t)n*64 + lane];
    __syncthreads();
    float acc = bpn[lane];
    for (int k = 0; k < 64; k++) acc = fmaf(rows[w][k], wp[k*64 + lane], acc);
    nb[(size_t)n*64 + lane] = f2b(acc);
    float pl[4], pr[4];
#pragma unroll
    for (int h = 0; h < 4; h++) { pl[h] = acc * Al[lane*4 + h]; pr[h] = acc * Ar[lane*4 + h]; }
#pragma unroll
    for (int off = 32; off > 0; off >>= 1) {
#pragma unroll
        for (int h = 0; h < 4; h++) {
            pl[h] += __shfl_xor(pl[h], off, 64);
            pr[h] += __shfl_xor(pr[h], off, 64);
        }
    }
    if (lane == 0) {
#pragma unroll
        for (int h = 0; h < 4; h++) { el[(size_t)n*4 + h] = pl[h]; er[(size_t)n*4 + h] = pr[h]; }
    }
}

__global__ void hist_kernel(const int* __restrict__ dst, int* __restrict__ deg)
{
    int e = blockIdx.x * 256 + threadIdx.x;
    if (e < N_EDGES) atomicAdd(&deg[dst[e]], 1);
}

__global__ __launch_bounds__(1024) void prefix_kernel(const int* __restrict__ deg,
                                                      int* __restrict__ offs, int* __restrict__ curs)
{
    __shared__ int wsum[16];
    __shared__ int carry_s;
    int tid = threadIdx.x, lane = tid & 63, w = tid >> 6;
    if (tid == 0) carry_s = 0;
    __syncthreads();
    for (int base = 0; base < N_NODES; base += 1024) {
        int i = base + tid;
        int v = (i < N_NODES) ? deg[i] : 0;
        int incl = v;
#pragma unroll
        for (int off = 1; off < 64; off <<= 1) {
            int y = __shfl_up(incl, off, 64);
            if (lane >= off) incl += y;
        }
        if (lane == 63) wsum[w] = incl;
        __syncthreads();
        int c0 = carry_s;
        int woff = 0;
#pragma unroll
        for (int k = 0; k < 15; k++) woff += (k < w) ? wsum[k] : 0;
        int ex = c0 + woff + incl - v;
        if (i < N_NODES) { offs[i] = ex; curs[i] = ex; }
        __syncthreads();
        if (tid == 1023) carry_s = c0 + woff + incl;
        __syncthreads();
    }
    if (tid == 0) offs[N_NODES] = carry_s;
}

__global__ void fill_kernel(const int* __restrict__ dst, int* __restrict__ curs, int* __restrict__ csr)
{
    int e = blockIdx.x * 256 + threadIdx.x;
    if (e < N_EDGES) {
        int slot = atomicAdd(&curs[dst[e]], 1);
        csr[slot] = e;
    }
}

// thread per CSR slot: logits (leaky applied) + srcs + bf16 edge row, all written coalesced
__global__ __launch_bounds__(256) void logit_kernel(
    const int* __restrict__ csr, const int* __restrict__ src, const int* __restrict__ dst,
    const float* __restrict__ edge_feat, const float* __restrict__ el, const float* __restrict__ er,
    const float* __restrict__ B, const float* __restrict__ Ce,
    float4* __restrict__ lp, int* __restrict__ srcs, ushort_t* __restrict__ efb)
{
    int j = blockIdx.x * 256 + threadIdx.x;
    if (j >= N_EDGES) return;
    int eid = csr[j];
    int sn = src[eid], dn = dst[eid];
    const float4* el4 = (const float4*)el;
    const float4* er4 = (const float4*)er;
    float4 a = el4[sn];
    float4 b = er4[dn];
    float l0 = Ce[0] + a.x + b.x;
    float l1 = Ce[1] + a.y + b.y;
    float l2 = Ce[2] + a.z + b.z;
    float l3 = Ce[3] + a.w + b.w;
    const float4* ef4 = (const float4*)(edge_feat + (size_t)eid * 16);
    float4 e0 = ef4[0], e1 = ef4[1], e2 = ef4[2], e3 = ef4[3];
    float ef[16] = {e0.x,e0.y,e0.z,e0.w, e1.x,e1.y,e1.z,e1.w,
                    e2.x,e2.y,e2.z,e2.w, e3.x,e3.y,e3.z,e3.w};
#pragma unroll
    for (int k = 0; k < 16; k++) {
        float f = ef[k];
        l0 = fmaf(f, B[k*4 + 0], l0);
        l1 = fmaf(f, B[k*4 + 1], l1);
        l2 = fmaf(f, B[k*4 + 2], l2);
        l3 = fmaf(f, B[k*4 + 3], l3);
    }
    l0 = (l0 > 0.f) ? l0 : 0.2f * l0;
    l1 = (l1 > 0.f) ? l1 : 0.2f * l1;
    l2 = (l2 > 0.f) ? l2 : 0.2f * l2;
    l3 = (l3 > 0.f) ? l3 : 0.2f * l3;
    lp[j] = make_float4(l0, l1, l2, l3);
    srcs[j] = sn;
    uint_t pk[8];
#pragma unroll
    for (int k = 0; k < 8; k++)
        pk[k] = (uint_t)f2b(ef[2*k]) | ((uint_t)f2b(ef[2*k+1]) << 16);
    uint4* ev = (uint4*)(efb + (size_t)j * 16);
    ev[0] = make_uint4(pk[0], pk[1], pk[2], pk[3]);
    ev[1] = make_uint4(pk[4], pk[5], pk[6], pk[7]);
}

// wave per node: softmax + accumulate t (4x64) and q (16), all streams coalesced,
// only gather is the 128B bf16 node row
__global__ __launch_bounds__(256) void accum_kernel(
    const int* __restrict__ offs, const int* __restrict__ srcs,
    const ushort_t* __restrict__ efb, const float4* __restrict__ lp,
    const ushort_t* __restrict__ nb, ushort_t* __restrict__ u)
{
    int wid = blockIdx.x * 4 + (threadIdx.x >> 6);
    wid = __builtin_amdgcn_readfirstlane(wid);
    if (wid >= N_NODES) return;
    int lane = threadIdx.x & 63;
    int start = offs[wid], end = offs[wid + 1];
    int deg = end - start;

    float m[4], z[4], pe[4];
    int sn_l = 0;
    bool fast = (deg <= 64);
    if (fast) {
        float4 lv = (lane < deg) ? lp[start + lane]
                                 : make_float4(-1e30f, -1e30f, -1e30f, -1e30f);
        sn_l = (lane < deg) ? srcs[start + lane] : 0;
        float M[4] = {lv.x, lv.y, lv.z, lv.w};
#pragma unroll
        for (int off = 32; off > 0; off >>= 1) {
#pragma unroll
            for (int h = 0; h < 4; h++) M[h] = fmaxf(M[h], __shfl_xor(M[h], off, 64));
        }
        float lvv[4] = {lv.x, lv.y, lv.z, lv.w};
#pragma unroll
        for (int h = 0; h < 4; h++) pe[h] = (lane < deg) ? __expf(lvv[h] - M[h]) : 0.f;
        float Z[4] = {pe[0], pe[1], pe[2], pe[3]};
#pragma unroll
        for (int off = 32; off > 0; off >>= 1) {
#pragma unroll
            for (int h = 0; h < 4; h++) Z[h] += __shfl_xor(Z[h], off, 64);
        }
#pragma unroll
        for (int h = 0; h < 4; h++) { m[h] = M[h]; z[h] = Z[h]; }
    } else {
#pragma unroll
        for (int h = 0; h < 4; h++) { m[h] = -1e30f; z[h] = 0.f; }
        for (int base = start; base < end; base += 64) {
            int j = base + lane;
            float4 lv = (j < end) ? lp[j] : make_float4(-1e30f, -1e30f, -1e30f, -1e30f);
            float M[4] = {lv.x, lv.y, lv.z, lv.w};
#pragma unroll
            for (int off = 32; off > 0; off >>= 1) {
#pragma unroll
                for (int h = 0; h < 4; h++) M[h] = fmaxf(M[h], __shfl_xor(M[h], off, 64));
            }
            float lvv[4] = {lv.x, lv.y, lv.z, lv.w};
            float P[4];
#pragma unroll
            for (int h = 0; h < 4; h++) P[h] = (j < end) ? __expf(lvv[h] - M[h]) : 0.f;
#pragma unroll
            for (int off = 32; off > 0; off >>= 1) {
#pragma unroll
                for (int h = 0; h < 4; h++) P[h] += __shfl_xor(P[h], off, 64);
            }
#pragma unroll
            for (int h = 0; h < 4; h++) {
                float nm = fmaxf(m[h], M[h]);
                z[h] = z[h] * __expf(m[h] - nm) + P[h] * __expf(M[h] - nm);
                m[h] = nm;
            }
        }
    }
    float zinv[4];
#pragma unroll
    for (int h = 0; h < 4; h++) zinv[h] = (z[h] > 0.f) ? 1.f / z[h] : 0.f;

    float t0 = 0.f, t1 = 0.f, t2 = 0.f, t3 = 0.f, qa = 0.f;
    int qh = lane >> 4, qk = lane & 15;

    if (fast) {
#pragma unroll 2
        for (int jj = 0; jj < deg; ++jj) {
            int sn = __shfl(sn_l, jj, 64);
            float a0 = __shfl(pe[0], jj, 64);
            float a1 = __shfl(pe[1], jj, 64);
            float a2 = __shfl(pe[2], jj, 64);
            float a3 = __shfl(pe[3], jj, 64);
            float nd = b2f(nb[(size_t)sn*64 + lane]);
            t0 = fmaf(a0, nd, t0);
            t1 = fmaf(a1, nd, t1);
            t2 = fmaf(a2, nd, t2);
            t3 = fmaf(a3, nd, t3);
            float efv = b2f(efb[(size_t)(start + jj)*16 + qk]);
            float ah = (qh < 2) ? ((qh == 0) ? a0 : a1) : ((qh == 2) ? a2 : a3);
            qa = fmaf(ah, efv, qa);
        }
    } else {
        for (int j = start; j < end; ++j) {
            float4 lv = lp[j];
            int sn = srcs[j];
            float a0 = __expf(lv.x - m[0]);
            float a1 = __expf(lv.y - m[1]);
            float a2 = __expf(lv.z - m[2]);
            float a3 = __expf(lv.w - m[3]);
            float nd = b2f(nb[(size_t)sn*64 + lane]);
            t0 = fmaf(a0, nd, t0);
            t1 = fmaf(a1, nd, t1);
            t2 = fmaf(a2, nd, t2);
            t3 = fmaf(a3, nd, t3);
            float efv = b2f(efb[(size_t)j*16 + qk]);
            float ah = (qh < 2) ? ((qh == 0) ? a0 : a1) : ((qh == 2) ? a2 : a3);
            qa = fmaf(ah, efv, qa);
        }
    }
    ushort_t* up = u + (size_t)wid * 320;
    up[0*64 + lane] = f2b(t0 * zinv[0]);
    up[1*64 + lane] = f2b(t1 * zinv[1]);
    up[2*64 + lane] = f2b(t2 * zinv[2]);
    up[3*64 + lane] = f2b(t3 * zinv[3]);
    up[256 + lane]  = f2b(qa * zinv[qh]);
}

// rst(bf16) = silu( t@fcW_h + q@Wqe_h + flag*Cb + bias ), BN partials in f32
__global__ __launch_bounds__(256) void conv_kernel(
    const ushort_t* __restrict__ u, const float* __restrict__ fcw2, const float* __restrict__ Wqe,
    const float* __restrict__ Cb, const float* __restrict__ convb2, const int* __restrict__ offs,
    ushort_t* __restrict__ rst, float* __restrict__ scr)
{
    __shared__ float ul[16 * 320];
    __shared__ float red[512];
    __shared__ float fl[16];
    int tid = threadIdx.x;
    int n0 = blockIdx.x * 16;
    const uint_t* ub = (const uint_t*)(u + (size_t)n0 * 320);
    for (int i = tid; i < 16*160; i += 256) {
        uint_t v = ub[i];
        ul[2*i]     = b2f((ushort_t)(v & 0xffff));
        ul[2*i + 1] = b2f((ushort_t)(v >> 16));
    }
    if (tid < 16) fl[tid] = (offs[n0 + tid + 1] > offs[n0 + tid]) ? 1.f : 0.f;
    __syncthreads();
    int c = tid, h = tid >> 6, cc = tid & 63;
    float acc[16];
#pragma unroll
    for (int t2 = 0; t2 < 16; t2++) acc[t2] = 0.f;
    for (int k = 0; k < 64; k++) {
        float wA = fcw2[k*256 + c];
#pragma unroll
        for (int t2 = 0; t2 < 16; t2++) acc[t2] = fmaf(wA, ul[t2*320 + h*64 + k], acc[t2]);
    }
    for (int k = 0; k < 16; k++) {
        float wq = Wqe[h*1024 + k*64 + cc];
#pragma unroll
        for (int t2 = 0; t2 < 16; t2++) acc[t2] = fmaf(wq, ul[t2*320 + 256 + h*16 + k], acc[t2]);
    }
    float bias = convb2[c], cb = Cb[c];
    float psumv = 0.f, psqv = 0.f;
#pragma unroll
    for (int t2 = 0; t2 < 16; t2++) {
        float v = acc[t2] + bias + fl[t2] * cb;
        float r = v / (1.f + __expf(-v));
        rst[(size_t)(n0 + t2)*256 + c] = f2b(r);
        psumv += r; psqv += r * r;
    }
    red[c] = psumv; red[256 + c] = psqv;
    __syncthreads();
    if (tid < 64) {
        float sgm = red[tid] + red[64+tid] + red[128+tid] + red[192+tid];
        float sq  = red[256+tid] + red[320+tid] + red[384+tid] + red[448+tid];
        scr[(size_t)blockIdx.x*128 + tid]      = sgm;
        scr[(size_t)blockIdx.x*128 + 64 + tid] = sq;
    }
}

__global__ __launch_bounds__(128) void scr_reduce_kernel(const float* __restrict__ scr,
                                                         float* __restrict__ scr2)
{
    int b = blockIdx.x, tid = threadIdx.x;
    float s = 0.f;
    for (int r = b; r < N_NODES/16; r += 128) s += scr[(size_t)r*128 + tid];
    scr2[(size_t)b*128 + tid] = s;
}

__global__ void bn_finalize_kernel(const float* __restrict__ scr2, const float* __restrict__ gamma2,
                                   const float* __restrict__ beta2, float* __restrict__ ss)
{
    __shared__ float part[8][128];
    __shared__ float tot[128];
    int j = threadIdx.x & 127, chunk = threadIdx.x >> 7;
    float t = 0.f;
    for (int b = chunk; b < 128; b += 8) t += scr2[(size_t)b*128 + j];
    part[chunk][j] = t;
    __syncthreads();
    if (threadIdx.x < 128) {
        float sgm = 0.f;
        for (int c = 0; c < 8; c++) sgm += part[c][threadIdx.x];
        tot[threadIdx.x] = sgm;
    }
    __syncthreads();
    if (threadIdx.x < 64) {
        float inv = 1.f / (float)(N_NODES * HEADS);
        float mean = tot[threadIdx.x] * inv;
        float var  = tot[64 + threadIdx.x] * inv - mean * mean;
        float sc = gamma2[threadIdx.x] * rsqrtf(var + 1e-5f);
        ss[threadIdx.x]      = sc;
        ss[64 + threadIdx.x] = beta2[threadIdx.x] - mean * sc;
    }
}

__global__ __launch_bounds__(256) void head_kernel(
    const ushort_t* __restrict__ rst, const float* __restrict__ ss,
    const float* __restrict__ headw, const float* __restrict__ headb,
    float* __restrict__ x)
{
    __shared__ float xl[16 * 256];
    int tid = threadIdx.x;
    int n0 = blockIdx.x * 16;
    const uint_t* rb = (const uint_t*)(rst + (size_t)n0 * 256);
    for (int i = tid; i < 16*128; i += 256) {
        uint_t v = rb[i];
        int e0 = 2*i, e1 = 2*i + 1;
        int ch0 = e0 & 63;
        xl[e0] = fmaf(b2f((ushort_t)(v & 0xffff)), ss[ch0],     ss[64 + ch0]);
        xl[e1] = fmaf(b2f((ushort_t)(v >> 16)),    ss[ch0 + 1], ss[64 + ch0 + 1]);
    }
    __syncthreads();
    int c = tid & 63, g = tid >> 6;
    float hb = headb[c];
    float a[4] = {hb, hb, hb, hb};
    for (int k = 0; k < 256; k++) {
        float w = headw[k*64 + c];
#pragma unroll
        for (int t2 = 0; t2 < 4; t2++) a[t2] = fmaf(w, xl[(g*4 + t2)*256 + k], a[t2]);
    }
#pragma unroll
    for (int t2 = 0; t2 < 4; t2++) {
        int n = n0 + g*4 + t2;
        x[(size_t)n*64 + c] = a[t2];
    }
}

__global__ void bounds_kernel(const int* __restrict__ gids, int* __restrict__ gstart)
{
    int g = threadIdx.x;
    if (g > N_GRAPHS) return;
    int lo = 0, hi = N_NODES;
    while (lo < hi) { int mid = (lo + hi) >> 1; if (gids[mid] < g) lo = mid + 1; else hi = mid; }
    gstart[g] = lo;
}

__global__ __launch_bounds__(1024) void pool_kernel(const float* __restrict__ x,
                                                    const int* __restrict__ gstart,
                                                    float* __restrict__ out)
{
    __shared__ float red[16][64];
    int g = blockIdx.x;
    int lane = threadIdx.x & 63, w = threadIdx.x >> 6;
    int s = gstart[g], e = gstart[g + 1];
    float acc = 0.f;
    for (int n = s + w; n < e; n += 16) acc += x[(size_t)n*64 + lane];
    red[w][lane] = acc;
    __syncthreads();
    if (w == 0) {
        float t = 0.f;
#pragma unroll
        for (int k = 0; k < 16; k++) t += red[k][lane];
        float c = (float)(e - s);
        out[(size_t)g*64 + lane] = t / fmaxf(c, 1.f);
    }
}

__global__ void gather_kernel(const float* __restrict__ x, const int* __restrict__ nidx,
                              float* __restrict__ outq)
{
    int i = blockIdx.x * 256 + threadIdx.x;
    if (i < N_QUERY * HID) {
        int q = i >> 6, c = i & 63;
        outq[i] = x[(size_t)nidx[q]*64 + c];
    }
}

extern "C" void kernel_launch(void* const* d_in, const int* in_sizes, int n_in,
                              void* d_out, int out_size, void* d_ws, size_t ws_size,
                              hipStream_t stream)
{
    const float* node_feat   = (const float*)d_in[0];
    const float* edge_feat   = (const float*)d_in[1];
    const float* node_proj_w = (const float*)d_in[2];
    const float* node_proj_b = (const float*)d_in[3];
    const float* edge_proj_w = (const float*)d_in[4];
    const float* edge_proj_b = (const float*)d_in[5];
    const float* fc_w        = (const float*)d_in[6];
    const float* fc_edge_w   = (const float*)d_in[7];
    const float* attn_l      = (const float*)d_in[8];
    const float* attn_r      = (const float*)d_in[9];
    const float* attn_e      = (const float*)d_in[10];
    const float* conv_bias   = (const float*)d_in[11];
    const float* bn_gamma    = (const float*)d_in[12];
    const float* bn_beta     = (const float*)d_in[13];
    const float* head_w      = (const float*)d_in[14];
    const float* head_b      = (const float*)d_in[15];
    const int*   src         = (const int*)d_in[16];
    const int*   dst         = (const int*)d_in[17];
    const int*   gids        = (const int*)d_in[18];
    const int*   nidx        = (const int*)d_in[19];

    if (ws_size < WS_TOTAL * sizeof(float)) return;

    float* ws  = (float*)d_ws;
    float* out = (float*)d_out;

    const int L2 = 2;
    const float* fcw2   = fc_w      + (size_t)L2 * HID * HEADS * HID;
    const float* fcew2  = fc_edge_w + (size_t)L2 * HID * HEADS * HID;
    const float* attl2  = attn_l    + (size_t)L2 * HEADS * HID;
    const float* attr2  = attn_r    + (size_t)L2 * HEADS * HID;
    const float* atte2  = attn_e    + (size_t)L2 * HEADS * HID;
    const float* convb2 = conv_bias + (size_t)L2 * HEADS * HID;
    const float* gamma2 = bn_gamma  + (size_t)L2 * HID;
    const float* beta2  = bn_beta   + (size_t)L2 * HID;

    int*   deg    = (int*)(ws + OFF_DEG);
    int*   gstart = (int*)(ws + OFF_GST);
    int*   offs   = (int*)(ws + OFF_OFFS);
    int*   curs   = (int*)(ws + OFF_CURS);
    int*   csr    = (int*)(ws + OFF_CSR);
    int*   srcs   = (int*)(ws + OFF_SRCS);
    float* Al     = ws + OFF_AL;
    float* Ar     = ws + OFF_AR;
    float* Bm     = ws + OFF_B;
    float* Ce     = ws + OFF_CE;
    float* Cb     = ws + OFF_CB;
    float* Wqe    = ws + OFF_WQE;
    float* ss     = ws + OFF_SS;
    float* el     = ws + OFF_EL;
    float* er     = ws + OFF_ER;
    ushort_t* nb  = (ushort_t*)(ws + OFF_NB);
    float4* lp    = (float4*)(ws + OFF_LP);
    ushort_t* efb = (ushort_t*)(ws + OFF_EFB);
    ushort_t* u   = (ushort_t*)(ws + OFF_U);
    ushort_t* rst = (ushort_t*)(ws + OFF_RST);
    float* x      = ws + OFF_X;
    float* scr    = ws + OFF_SCR;
    float* scr2   = ws + OFF_SCR2;

    hipMemsetAsync(d_ws, 0, N_NODES * sizeof(int), stream);   // deg = 0

    precompute_kernel<<<1, 256, 0, stream>>>(fcw2, fcew2, attl2, attr2, atte2,
                                             edge_proj_w, edge_proj_b,
                                             Al, Ar, Bm, Ce, Cb, Wqe);
    bounds_kernel<<<1, 64, 0, stream>>>(gids, gstart);
    node_proj_kernel<<<N_NODES/4, 256, 0, stream>>>(node_feat, node_proj_w, node_proj_b,
                                                    Al, Ar, nb, el, er);
    hist_kernel<<<(N_EDGES + 255)/256, 256, 0, stream>>>(dst, deg);
    prefix_kernel<<<1, 1024, 0, stream>>>(deg, offs, curs);
    fill_kernel<<<(N_EDGES + 255)/256, 256, 0, stream>>>(dst, curs, csr);
    logit_kernel<<<(N_EDGES + 255)/256, 256, 0, stream>>>(csr, src, dst, edge_feat,
                                                          el, er, Bm, Ce, lp, srcs, efb);
    accum_kernel<<<N_NODES/4, 256, 0, stream>>>(offs, srcs, efb, lp, nb, u);
    conv_kernel<<<N_NODES/16, 256, 0, stream>>>(u, fcw2, Wqe, Cb, convb2, offs, rst, scr);
    scr_reduce_kernel<<<128, 128, 0, stream>>>(scr, scr2);
    bn_finalize_kernel<<<1, 1024, 0, stream>>>(scr2, gamma2, beta2, ss);
    head_kernel<<<N_NODES/16, 256, 0, stream>>>(rst, ss, head_w, head_b, x);
    pool_kernel<<<N_GRAPHS, 1024, 0, stream>>>(x, gstart, out);
    gather_kernel<<<(N_QUERY*HID + 255)/256, 256, 0, stream>>>(x, nidx, out + N_GRAPHS*HID);
}

// Round 5
// 442.945 us; speedup vs baseline: 2.6212x; 1.0576x over previous
//
#include <hip/hip_runtime.h>
#include <cstdint>
#include <cstddef>

#define N_NODES 50000
#define N_EDGES 800000
#define HID 64
#define HEADS 4
#define N_GRAPHS 32
#define N_QUERY 4096

typedef unsigned short ushort_t;
typedef unsigned int uint_t;

__device__ __forceinline__ float b2f(ushort_t h) { return __uint_as_float(((uint_t)h) << 16); }
__device__ __forceinline__ ushort_t f2b(float f) {
    uint_t u = __float_as_uint(f);
    uint_t r = (u + 0x7FFFu + ((u >> 16) & 1u)) >> 16;
    return (ushort_t)r;
}

// ---- workspace layout (4-byte element offsets) ----
static constexpr size_t OFF_DEG   = 0;          // int[50000]
static constexpr size_t OFF_GST   = 50016;      // int[33]
static constexpr size_t OFF_OFFS  = 50064;      // int[50001]
static constexpr size_t OFF_CURS  = 100080;     // int[50000]
static constexpr size_t OFF_SLOT  = 150080;     // int[800000]  eid -> slot
static constexpr size_t OFF_SRCS  = 950080;     // int[800064]  (+64 pad)
static constexpr size_t OFF_AL    = 1750144;    // float[256]
static constexpr size_t OFF_AR    = 1750400;    // float[256]
static constexpr size_t OFF_B     = 1750656;    // float[64]
static constexpr size_t OFF_CE    = 1750720;    // float[16]
static constexpr size_t OFF_CB    = 1750736;    // float[256]
static constexpr size_t OFF_WQE   = 1750992;    // float[4096]
static constexpr size_t OFF_SS    = 1755088;    // float[128]
static constexpr size_t OFF_EL    = 1755216;    // float[200000]
static constexpr size_t OFF_ER    = 1955216;    // float[200000]
static constexpr size_t OFF_NB    = 2155216;    // bf16[50000*64]
static constexpr size_t OFF_LP    = 3755216;    // float4[800064]
static constexpr size_t OFF_EFB   = 6955472;    // bf16[800064*16]
static constexpr size_t OFF_U     = 13355984;   // bf16[50000*320]
static constexpr size_t OFF_RST   = 21355984;   // bf16[50000*256]
static constexpr size_t OFF_X     = 27755984;   // float[3200000]
static constexpr size_t OFF_SCR   = 30955984;   // float[400000]
static constexpr size_t OFF_SCR2  = 31355984;   // float[16384]
static constexpr size_t WS_TOTAL  = 31372368;   // elements (~125.5 MB)

__global__ void precompute_kernel(const float* __restrict__ fcw2, const float* __restrict__ fcew2,
                                  const float* __restrict__ attl2, const float* __restrict__ attr2,
                                  const float* __restrict__ atte2,
                                  const float* __restrict__ wpe, const float* __restrict__ bpe,
                                  float* __restrict__ Al, float* __restrict__ Ar,
                                  float* __restrict__ B, float* __restrict__ Ce,
                                  float* __restrict__ Cb, float* __restrict__ Wqe)
{
    __shared__ float AE[256];
    int tid = threadIdx.x;
    int c = tid >> 2, h = tid & 3;
    float al = 0.f, ar = 0.f, ae = 0.f;
    for (int d = 0; d < 64; d++) {
        float wl = fcw2[c*256 + h*64 + d];
        float we = fcew2[c*256 + h*64 + d];
        al = fmaf(wl, attl2[h*64 + d], al);
        ar = fmaf(wl, attr2[h*64 + d], ar);
        ae = fmaf(we, atte2[h*64 + d], ae);
    }
    Al[c*4 + h] = al;
    Ar[c*4 + h] = ar;
    AE[c*4 + h] = ae;
    __syncthreads();
    if (tid < 64) {
        int kk = tid >> 2, hh = tid & 3;
        float b = 0.f;
        for (int d = 0; d < 64; d++) b = fmaf(wpe[kk*64 + d], AE[d*4 + hh], b);
        B[kk*4 + hh] = b;
    }
    if (tid < 4) {
        float ce = 0.f;
        for (int d = 0; d < 64; d++) ce = fmaf(bpe[d], AE[d*4 + tid], ce);
        Ce[tid] = ce;
    }
    {
        float cb = 0.f;
        for (int d = 0; d < 64; d++) cb = fmaf(bpe[d], fcew2[d*256 + tid], cb);
        Cb[tid] = cb;
    }
    for (int i = 0; i < 16; i++) {
        int idx = tid + i*256;
        int hh = idx >> 10, rem = idx & 1023, kk = rem >> 6, cc = rem & 63;
        float w = 0.f;
        for (int d = 0; d < 64; d++) w = fmaf(wpe[kk*64 + d], fcew2[d*256 + hh*64 + cc], w);
        Wqe[idx] = w;
    }
}

// nodes(bf16) = node_feat @ Wp + bp ; el/er = nodes @ Al/Ar
__global__ __launch_bounds__(256) void node_proj_kernel(
    const float* __restrict__ nf, const float* __restrict__ wp, const float* __restrict__ bpn,
    const float* __restrict__ Al, const float* __restrict__ Ar,
    ushort_t* __restrict__ nb, float* __restrict__ el, float* __restrict__ er)
{
    __shared__ float rows[4][64];
    int tid = threadIdx.x, w = tid >> 6, lane = tid & 63;
    int n = blockIdx.x * 4 + w;
    rows[w][lane] = nf[(size_t)n*64 + lane];
    __syncthreads();
    float acc = bpn[lane];
    for (int k = 0; k < 64; k++) acc = fmaf(rows[w][k], wp[k*64 + lane], acc);
    nb[(size_t)n*64 + lane] = f2b(acc);
    float pl[4], pr[4];
#pragma unroll
    for (int h = 0; h < 4; h++) { pl[h] = acc * Al[lane*4 + h]; pr[h] = acc * Ar[lane*4 + h]; }
#pragma unroll
    for (int off = 32; off > 0; off >>= 1) {
#pragma unroll
        for (int h = 0; h < 4; h++) {
            pl[h] += __shfl_xor(pl[h], off, 64);
            pr[h] += __shfl_xor(pr[h], off, 64);
        }
    }
    if (lane == 0) {
#pragma unroll
        for (int h = 0; h < 4; h++) { el[(size_t)n*4 + h] = pl[h]; er[(size_t)n*4 + h] = pr[h]; }
    }
}

__global__ void hist_kernel(const int* __restrict__ dst, int* __restrict__ deg)
{
    int e = blockIdx.x * 256 + threadIdx.x;
    if (e < N_EDGES) atomicAdd(&deg[dst[e]], 1);
}

__global__ __launch_bounds__(1024) void prefix_kernel(const int* __restrict__ deg,
                                                      int* __restrict__ offs, int* __restrict__ curs)
{
    __shared__ int wsum[16];
    __shared__ int carry_s;
    int tid = threadIdx.x, lane = tid & 63, w = tid >> 6;
    if (tid == 0) carry_s = 0;
    __syncthreads();
    for (int base = 0; base < N_NODES; base += 1024) {
        int i = base + tid;
        int v = (i < N_NODES) ? deg[i] : 0;
        int incl = v;
#pragma unroll
        for (int off = 1; off < 64; off <<= 1) {
            int y = __shfl_up(incl, off, 64);
            if (lane >= off) incl += y;
        }
        if (lane == 63) wsum[w] = incl;
        __syncthreads();
        int c0 = carry_s;
        int woff = 0;
#pragma unroll
        for (int k = 0; k < 15; k++) woff += (k < w) ? wsum[k] : 0;
        int ex = c0 + woff + incl - v;
        if (i < N_NODES) { offs[i] = ex; curs[i] = ex; }
        __syncthreads();
        if (tid == 1023) carry_s = c0 + woff + incl;
        __syncthreads();
    }
    if (tid == 0) offs[N_NODES] = carry_s;
}

// slot assignment + srcs in CSR order + eid->slot map
__global__ void fill_kernel(const int* __restrict__ src, const int* __restrict__ dst,
                            int* __restrict__ curs, int* __restrict__ slotmap,
                            int* __restrict__ srcs)
{
    int e = blockIdx.x * 256 + threadIdx.x;
    if (e < N_EDGES) {
        int slot = atomicAdd(&curs[dst[e]], 1);
        slotmap[e] = slot;
        srcs[slot] = src[e];
    }
}

// eid-order: coalesced edge_feat stream, scatter lp/efb to CSR slots
__global__ __launch_bounds__(256) void logit_kernel(
    const int* __restrict__ slotmap, const int* __restrict__ src, const int* __restrict__ dst,
    const float* __restrict__ edge_feat, const float* __restrict__ el, const float* __restrict__ er,
    const float* __restrict__ B, const float* __restrict__ Ce,
    float4* __restrict__ lp, ushort_t* __restrict__ efb)
{
    int e = blockIdx.x * 256 + threadIdx.x;
    if (e >= N_EDGES) return;
    int sn = src[e], dn = dst[e];
    const float4* el4 = (const float4*)el;
    const float4* er4 = (const float4*)er;
    float4 a = el4[sn];
    float4 b = er4[dn];
    float l0 = Ce[0] + a.x + b.x;
    float l1 = Ce[1] + a.y + b.y;
    float l2 = Ce[2] + a.z + b.z;
    float l3 = Ce[3] + a.w + b.w;
    const float4* ef4 = (const float4*)(edge_feat + (size_t)e * 16);
    float4 e0 = ef4[0], e1 = ef4[1], e2 = ef4[2], e3 = ef4[3];
    float ef[16] = {e0.x,e0.y,e0.z,e0.w, e1.x,e1.y,e1.z,e1.w,
                    e2.x,e2.y,e2.z,e2.w, e3.x,e3.y,e3.z,e3.w};
#pragma unroll
    for (int k = 0; k < 16; k++) {
        float f = ef[k];
        l0 = fmaf(f, B[k*4 + 0], l0);
        l1 = fmaf(f, B[k*4 + 1], l1);
        l2 = fmaf(f, B[k*4 + 2], l2);
        l3 = fmaf(f, B[k*4 + 3], l3);
    }
    l0 = (l0 > 0.f) ? l0 : 0.2f * l0;
    l1 = (l1 > 0.f) ? l1 : 0.2f * l1;
    l2 = (l2 > 0.f) ? l2 : 0.2f * l2;
    l3 = (l3 > 0.f) ? l3 : 0.2f * l3;
    int slot = slotmap[e];
    lp[slot] = make_float4(l0, l1, l2, l3);
    uint_t pk[8];
#pragma unroll
    for (int k = 0; k < 8; k++)
        pk[k] = (uint_t)f2b(ef[2*k]) | ((uint_t)f2b(ef[2*k+1]) << 16);
    uint4* ev = (uint4*)(efb + (size_t)slot * 16);
    ev[0] = make_uint4(pk[0], pk[1], pk[2], pk[3]);
    ev[1] = make_uint4(pk[4], pk[5], pk[6], pk[7]);
}

// 16-lane group per node, 4 nodes/wave, 16 nodes/block.
// lane li owns channels 4li..4li+3; t[4][4], q[4] in regs.
__global__ __launch_bounds__(256) void accum_kernel(
    const int* __restrict__ offs, const int* __restrict__ srcs,
    const ushort_t* __restrict__ efb, const float4* __restrict__ lp,
    const ushort_t* __restrict__ nb, ushort_t* __restrict__ u)
{
    int tid = threadIdx.x;
    int lane = tid & 63;
    int li = lane & 15;
    int node = blockIdx.x * 16 + (tid >> 6) * 4 + ((lane >> 4) & 3);
    int start = offs[node], end = offs[node + 1];
    int deg = end - start;

    const float4 NEG = make_float4(-1e30f, -1e30f, -1e30f, -1e30f);
    float4 lv0 = (li < deg)      ? lp[start + li]      : NEG;
    float4 lv1 = (16 + li < deg) ? lp[start + 16 + li] : NEG;

    // pass 1: per-head max
    float m[4] = { fmaxf(lv0.x, lv1.x), fmaxf(lv0.y, lv1.y),
                   fmaxf(lv0.z, lv1.z), fmaxf(lv0.w, lv1.w) };
    for (int base = 32; base < deg; base += 16) {       // rare (deg>32)
        int i = base + li;
        if (i < deg) {
            float4 lv = lp[start + i];
            m[0] = fmaxf(m[0], lv.x); m[1] = fmaxf(m[1], lv.y);
            m[2] = fmaxf(m[2], lv.z); m[3] = fmaxf(m[3], lv.w);
        }
    }
#pragma unroll
    for (int off = 1; off < 16; off <<= 1) {
#pragma unroll
        for (int h = 0; h < 4; h++) m[h] = fmaxf(m[h], __shfl_xor(m[h], off, 64));
    }

    // pass 2: exp + sum (padding lanes auto-0 since lv = -1e30)
    float pe0[4] = { __expf(lv0.x - m[0]), __expf(lv0.y - m[1]),
                     __expf(lv0.z - m[2]), __expf(lv0.w - m[3]) };
    float pe1[4] = { __expf(lv1.x - m[0]), __expf(lv1.y - m[1]),
                     __expf(lv1.z - m[2]), __expf(lv1.w - m[3]) };
    float z[4] = { pe0[0] + pe1[0], pe0[1] + pe1[1], pe0[2] + pe1[2], pe0[3] + pe1[3] };
    for (int base = 32; base < deg; base += 16) {       // rare
        int i = base + li;
        if (i < deg) {
            float4 lv = lp[start + i];
            z[0] += __expf(lv.x - m[0]); z[1] += __expf(lv.y - m[1]);
            z[2] += __expf(lv.z - m[2]); z[3] += __expf(lv.w - m[3]);
        }
    }
#pragma unroll
    for (int off = 1; off < 16; off <<= 1) {
#pragma unroll
        for (int h = 0; h < 4; h++) z[h] += __shfl_xor(z[h], off, 64);
    }
    float zinv[4];
#pragma unroll
    for (int h = 0; h < 4; h++) {
        zinv[h] = (z[h] > 0.f) ? 1.f / z[h] : 0.f;
        pe0[h] *= zinv[h];
        pe1[h] *= zinv[h];
    }

    // wave-uniform loop bound
    int mdeg = deg;
#pragma unroll
    for (int off = 1; off < 64; off <<= 1) mdeg = max(mdeg, __shfl_xor(mdeg, off, 64));
    mdeg = __builtin_amdgcn_readfirstlane(mdeg);

    float t[4][4] = {{0.f}};
    float q[4] = {0.f, 0.f, 0.f, 0.f};
    int grpbase = lane & 48;

    for (int j = 0; j < mdeg; ++j) {
        bool act = j < deg;
        float a0, a1, a2, a3;
        if (j < 32) {                                   // uniform branch
            float v0 = (j < 16) ? pe0[0] : pe1[0];
            float v1 = (j < 16) ? pe0[1] : pe1[1];
            float v2 = (j < 16) ? pe0[2] : pe1[2];
            float v3 = (j < 16) ? pe0[3] : pe1[3];
            int sl = grpbase | (j & 15);
            a0 = __shfl(v0, sl, 64);                    // 0 for padded lanes
            a1 = __shfl(v1, sl, 64);
            a2 = __shfl(v2, sl, 64);
            a3 = __shfl(v3, sl, 64);
        } else {                                        // rare
            a0 = a1 = a2 = a3 = 0.f;
            if (act) {
                float4 l4 = lp[start + j];
                a0 = __expf(l4.x - m[0]) * zinv[0];
                a1 = __expf(l4.y - m[1]) * zinv[1];
                a2 = __expf(l4.z - m[2]) * zinv[2];
                a3 = __expf(l4.w - m[3]) * zinv[3];
            }
        }
        int sidx = start + j;                           // padded arrays: always in-bounds
        int sn = srcs[sidx];
        sn = act ? sn : 0;
        ushort4 nv = *(const ushort4*)&nb[(size_t)sn*64 + li*4];
        float nd0 = b2f(nv.x), nd1 = b2f(nv.y), nd2 = b2f(nv.z), nd3 = b2f(nv.w);
        t[0][0] = fmaf(a0, nd0, t[0][0]); t[0][1] = fmaf(a0, nd1, t[0][1]);
        t[0][2] = fmaf(a0, nd2, t[0][2]); t[0][3] = fmaf(a0, nd3, t[0][3]);
        t[1][0] = fmaf(a1, nd0, t[1][0]); t[1][1] = fmaf(a1, nd1, t[1][1]);
        t[1][2] = fmaf(a1, nd2, t[1][2]); t[1][3] = fmaf(a1, nd3, t[1][3]);
        t[2][0] = fmaf(a2, nd0, t[2][0]); t[2][1] = fmaf(a2, nd1, t[2][1]);
        t[2][2] = fmaf(a2, nd2, t[2][2]); t[2][3] = fmaf(a2, nd3, t[2][3]);
        t[3][0] = fmaf(a3, nd0, t[3][0]); t[3][1] = fmaf(a3, nd1, t[3][1]);
        t[3][2] = fmaf(a3, nd2, t[3][2]); t[3][3] = fmaf(a3, nd3, t[3][3]);
        float efv = b2f(efb[(size_t)sidx*16 + li]);
        q[0] = fmaf(a0, efv, q[0]);
        q[1] = fmaf(a1, efv, q[1]);
        q[2] = fmaf(a2, efv, q[2]);
        q[3] = fmaf(a3, efv, q[3]);
    }

    ushort_t* up = u + (size_t)node * 320;
#pragma unroll
    for (int h = 0; h < 4; h++) {
        ushort4 tv;
        tv.x = f2b(t[h][0]); tv.y = f2b(t[h][1]);
        tv.z = f2b(t[h][2]); tv.w = f2b(t[h][3]);
        *(ushort4*)&up[h*64 + li*4] = tv;
        up[256 + h*16 + li] = f2b(q[h]);
    }
}

// rst(bf16) = silu( t@fcW_h + q@Wqe_h + flag*Cb + bias ), BN partials in f32
__global__ __launch_bounds__(256) void conv_kernel(
    const ushort_t* __restrict__ u, const float* __restrict__ fcw2, const float* __restrict__ Wqe,
    const float* __restrict__ Cb, const float* __restrict__ convb2, const int* __restrict__ offs,
    ushort_t* __restrict__ rst, float* __restrict__ scr)
{
    __shared__ float ul[16 * 320];
    __shared__ float red[512];
    __shared__ float fl[16];
    int tid = threadIdx.x;
    int n0 = blockIdx.x * 16;
    const uint_t* ub = (const uint_t*)(u + (size_t)n0 * 320);
    for (int i = tid; i < 16*160; i += 256) {
        uint_t v = ub[i];
        ul[2*i]     = b2f((ushort_t)(v & 0xffff));
        ul[2*i + 1] = b2f((ushort_t)(v >> 16));
    }
    if (tid < 16) fl[tid] = (offs[n0 + tid + 1] > offs[n0 + tid]) ? 1.f : 0.f;
    __syncthreads();
    int c = tid, h = tid >> 6, cc = tid & 63;
    float acc[16];
#pragma unroll
    for (int t2 = 0; t2 < 16; t2++) acc[t2] = 0.f;
    for (int k = 0; k < 64; k++) {
        float wA = fcw2[k*256 + c];
#pragma unroll
        for (int t2 = 0; t2 < 16; t2++) acc[t2] = fmaf(wA, ul[t2*320 + h*64 + k], acc[t2]);
    }
    for (int k = 0; k < 16; k++) {
        float wq = Wqe[h*1024 + k*64 + cc];
#pragma unroll
        for (int t2 = 0; t2 < 16; t2++) acc[t2] = fmaf(wq, ul[t2*320 + 256 + h*16 + k], acc[t2]);
    }
    float bias = convb2[c], cb = Cb[c];
    float psumv = 0.f, psqv = 0.f;
#pragma unroll
    for (int t2 = 0; t2 < 16; t2++) {
        float v = acc[t2] + bias + fl[t2] * cb;
        float r = v / (1.f + __expf(-v));
        rst[(size_t)(n0 + t2)*256 + c] = f2b(r);
        psumv += r; psqv += r * r;
    }
    red[c] = psumv; red[256 + c] = psqv;
    __syncthreads();
    if (tid < 64) {
        float sgm = red[tid] + red[64+tid] + red[128+tid] + red[192+tid];
        float sq  = red[256+tid] + red[320+tid] + red[384+tid] + red[448+tid];
        scr[(size_t)blockIdx.x*128 + tid]      = sgm;
        scr[(size_t)blockIdx.x*128 + 64 + tid] = sq;
    }
}

__global__ __launch_bounds__(128) void scr_reduce_kernel(const float* __restrict__ scr,
                                                         float* __restrict__ scr2)
{
    int b = blockIdx.x, tid = threadIdx.x;
    float s = 0.f;
    for (int r = b; r < N_NODES/16; r += 128) s += scr[(size_t)r*128 + tid];
    scr2[(size_t)b*128 + tid] = s;
}

__global__ void bn_finalize_kernel(const float* __restrict__ scr2, const float* __restrict__ gamma2,
                                   const float* __restrict__ beta2, float* __restrict__ ss)
{
    __shared__ float part[8][128];
    __shared__ float tot[128];
    int j = threadIdx.x & 127, chunk = threadIdx.x >> 7;
    float t = 0.f;
    for (int b = chunk; b < 128; b += 8) t += scr2[(size_t)b*128 + j];
    part[chunk][j] = t;
    __syncthreads();
    if (threadIdx.x < 128) {
        float sgm = 0.f;
        for (int c = 0; c < 8; c++) sgm += part[c][threadIdx.x];
        tot[threadIdx.x] = sgm;
    }
    __syncthreads();
    if (threadIdx.x < 64) {
        float inv = 1.f / (float)(N_NODES * HEADS);
        float mean = tot[threadIdx.x] * inv;
        float var  = tot[64 + threadIdx.x] * inv - mean * mean;
        float sc = gamma2[threadIdx.x] * rsqrtf(var + 1e-5f);
        ss[threadIdx.x]      = sc;
        ss[64 + threadIdx.x] = beta2[threadIdx.x] - mean * sc;
    }
}

__global__ __launch_bounds__(256) void head_kernel(
    const ushort_t* __restrict__ rst, const float* __restrict__ ss,
    const float* __restrict__ headw, const float* __restrict__ headb,
    float* __restrict__ x)
{
    __shared__ float xl[16 * 256];
    int tid = threadIdx.x;
    int n0 = blockIdx.x * 16;
    const uint_t* rb = (const uint_t*)(rst + (size_t)n0 * 256);
    for (int i = tid; i < 16*128; i += 256) {
        uint_t v = rb[i];
        int e0 = 2*i, e1 = 2*i + 1;
        int ch0 = e0 & 63;
        xl[e0] = fmaf(b2f((ushort_t)(v & 0xffff)), ss[ch0],     ss[64 + ch0]);
        xl[e1] = fmaf(b2f((ushort_t)(v >> 16)),    ss[ch0 + 1], ss[64 + ch0 + 1]);
    }
    __syncthreads();
    int c = tid & 63, g = tid >> 6;
    float hb = headb[c];
    float a[4] = {hb, hb, hb, hb};
    for (int k = 0; k < 256; k++) {
        float w = headw[k*64 + c];
#pragma unroll
        for (int t2 = 0; t2 < 4; t2++) a[t2] = fmaf(w, xl[(g*4 + t2)*256 + k], a[t2]);
    }
#pragma unroll
    for (int t2 = 0; t2 < 4; t2++) {
        int n = n0 + g*4 + t2;
        x[(size_t)n*64 + c] = a[t2];
    }
}

__global__ void bounds_kernel(const int* __restrict__ gids, int* __restrict__ gstart)
{
    int g = threadIdx.x;
    if (g > N_GRAPHS) return;
    int lo = 0, hi = N_NODES;
    while (lo < hi) { int mid = (lo + hi) >> 1; if (gids[mid] < g) lo = mid + 1; else hi = mid; }
    gstart[g] = lo;
}

__global__ __launch_bounds__(1024) void pool_kernel(const float* __restrict__ x,
                                                    const int* __restrict__ gstart,
                                                    float* __restrict__ out)
{
    __shared__ float red[16][64];
    int g = blockIdx.x;
    int lane = threadIdx.x & 63, w = threadIdx.x >> 6;
    int s = gstart[g], e = gstart[g + 1];
    float acc = 0.f;
    for (int n = s + w; n < e; n += 16) acc += x[(size_t)n*64 + lane];
    red[w][lane] = acc;
    __syncthreads();
    if (w == 0) {
        float t = 0.f;
#pragma unroll
        for (int k = 0; k < 16; k++) t += red[k][lane];
        float c = (float)(e - s);
        out[(size_t)g*64 + lane] = t / fmaxf(c, 1.f);
    }
}

__global__ void gather_kernel(const float* __restrict__ x, const int* __restrict__ nidx,
                              float* __restrict__ outq)
{
    int i = blockIdx.x * 256 + threadIdx.x;
    if (i < N_QUERY * HID) {
        int q = i >> 6, c = i & 63;
        outq[i] = x[(size_t)nidx[q]*64 + c];
    }
}

extern "C" void kernel_launch(void* const* d_in, const int* in_sizes, int n_in,
                              void* d_out, int out_size, void* d_ws, size_t ws_size,
                              hipStream_t stream)
{
    const float* node_feat   = (const float*)d_in[0];
    const float* edge_feat   = (const float*)d_in[1];
    const float* node_proj_w = (const float*)d_in[2];
    const float* node_proj_b = (const float*)d_in[3];
    const float* edge_proj_w = (const float*)d_in[4];
    const float* edge_proj_b = (const float*)d_in[5];
    const float* fc_w        = (const float*)d_in[6];
    const float* fc_edge_w   = (const float*)d_in[7];
    const float* attn_l      = (const float*)d_in[8];
    const float* attn_r      = (const float*)d_in[9];
    const float* attn_e      = (const float*)d_in[10];
    const float* conv_bias   = (const float*)d_in[11];
    const float* bn_gamma    = (const float*)d_in[12];
    const float* bn_beta     = (const float*)d_in[13];
    const float* head_w      = (const float*)d_in[14];
    const float* head_b      = (const float*)d_in[15];
    const int*   src         = (const int*)d_in[16];
    const int*   dst         = (const int*)d_in[17];
    const int*   gids        = (const int*)d_in[18];
    const int*   nidx        = (const int*)d_in[19];

    if (ws_size < WS_TOTAL * sizeof(float)) return;

    float* ws  = (float*)d_ws;
    float* out = (float*)d_out;

    const int L2 = 2;
    const float* fcw2   = fc_w      + (size_t)L2 * HID * HEADS * HID;
    const float* fcew2  = fc_edge_w + (size_t)L2 * HID * HEADS * HID;
    const float* attl2  = attn_l    + (size_t)L2 * HEADS * HID;
    const float* attr2  = attn_r    + (size_t)L2 * HEADS * HID;
    const float* atte2  = attn_e    + (size_t)L2 * HEADS * HID;
    const float* convb2 = conv_bias + (size_t)L2 * HEADS * HID;
    const float* gamma2 = bn_gamma  + (size_t)L2 * HID;
    const float* beta2  = bn_beta   + (size_t)L2 * HID;

    int*   deg     = (int*)(ws + OFF_DEG);
    int*   gstart  = (int*)(ws + OFF_GST);
    int*   offs    = (int*)(ws + OFF_OFFS);
    int*   curs    = (int*)(ws + OFF_CURS);
    int*   slotmap = (int*)(ws + OFF_SLOT);
    int*   srcs    = (int*)(ws + OFF_SRCS);
    float* Al      = ws + OFF_AL;
    float* Ar      = ws + OFF_AR;
    float* Bm      = ws + OFF_B;
    float* Ce      = ws + OFF_CE;
    float* Cb      = ws + OFF_CB;
    float* Wqe     = ws + OFF_WQE;
    float* ss      = ws + OFF_SS;
    float* el      = ws + OFF_EL;
    float* er      = ws + OFF_ER;
    ushort_t* nb   = (ushort_t*)(ws + OFF_NB);
    float4* lp     = (float4*)(ws + OFF_LP);
    ushort_t* efb  = (ushort_t*)(ws + OFF_EFB);
    ushort_t* u    = (ushort_t*)(ws + OFF_U);
    ushort_t* rst  = (ushort_t*)(ws + OFF_RST);
    float* x       = ws + OFF_X;
    float* scr     = ws + OFF_SCR;
    float* scr2    = ws + OFF_SCR2;

    hipMemsetAsync(d_ws, 0, N_NODES * sizeof(int), stream);   // deg = 0

    precompute_kernel<<<1, 256, 0, stream>>>(fcw2, fcew2, attl2, attr2, atte2,
                                             edge_proj_w, edge_proj_b,
                                             Al, Ar, Bm, Ce, Cb, Wqe);
    bounds_kernel<<<1, 64, 0, stream>>>(gids, gstart);
    node_proj_kernel<<<N_NODES/4, 256, 0, stream>>>(node_feat, node_proj_w, node_proj_b,
                                                    Al, Ar, nb, el, er);
    hist_kernel<<<(N_EDGES + 255)/256, 256, 0, stream>>>(dst, deg);
    prefix_kernel<<<1, 1024, 0, stream>>>(deg, offs, curs);
    fill_kernel<<<(N_EDGES + 255)/256, 256, 0, stream>>>(src, dst, curs, slotmap, srcs);
    logit_kernel<<<(N_EDGES + 255)/256, 256, 0, stream>>>(slotmap, src, dst, edge_feat,
                                                          el, er, Bm, Ce, lp, efb);
    accum_kernel<<<N_NODES/16, 256, 0, stream>>>(offs, srcs, efb, lp, nb, u);
    conv_kernel<<<N_NODES/16, 256, 0, stream>>>(u, fcw2, Wqe, Cb, convb2, offs, rst, scr);
    scr_reduce_kernel<<<128, 128, 0, stream>>>(scr, scr2);
    bn_finalize_kernel<<<1, 1024, 0, stream>>>(scr2, gamma2, beta2, ss);
    head_kernel<<<N_NODES/16, 256, 0, stream>>>(rst, ss, head_w, head_b, x);
    pool_kernel<<<N_GRAPHS, 1024, 0, stream>>>(x, gstart, out);
    gather_kernel<<<(N_QUERY*HID + 255)/256, 256, 0, stream>>>(x, nidx, out + N_GRAPHS*HID);
}